// Round 8
// baseline (6467.938 us; speedup 1.0000x reference)
//
#include <hip/hip_runtime.h>

#define B_ 4
#define T_ 2048
#define CH 64
#define NSL 64        // DV column-slices per batch
#define SLW 16        // columns per slice (NSL*SLW = 1024 = DV)

// ---------------------------------------------------------------------------
// QKV projection. 128x128 tile, 8x8 micro, BK=8. grid (rows/128, 8, 3).
// ---------------------------------------------------------------------------
__global__ __launch_bounds__(256) void gemm_qkv(
    const float* __restrict__ X,
    const float* __restrict__ W0, const float* __restrict__ W1, const float* __restrict__ W2,
    float* __restrict__ O0, float* __restrict__ O1, float* __restrict__ O2,
    int tg, int lsh)
{
  const int z = blockIdx.z;
  const float* W = (z == 0) ? W0 : ((z == 1) ? W1 : W2);
  float* O = (z == 0) ? O0 : ((z == 1) ? O1 : O2);
  const float scale = (z == 0) ? 0.03125f : 1.0f;
  const int r0 = blockIdx.x * 128;
  const int c0 = blockIdx.y * 128;
  const int tid = threadIdx.x;
  const int tx = tid & 15, ty = tid >> 4;

  __shared__ float As[8][132];
  __shared__ float Bs[8][132];

  float acc[8][8] = {};
  const int ar = tid >> 1;
  const int ak = (tid & 1) * 4;
  const int bk = tid >> 5;
  const int bn = (tid & 31) * 4;

  const int lr = r0 + ar;
  const int grow = ((lr >> lsh) << 11) + tg + (lr & ((1 << lsh) - 1));

  for (int k0 = 0; k0 < 1024; k0 += 8) {
    float4 a4 = *reinterpret_cast<const float4*>(&X[grow * 1024 + k0 + ak]);
    float4 b4 = *reinterpret_cast<const float4*>(&W[(k0 + bk) * 1024 + c0 + bn]);
    __syncthreads();
    As[ak + 0][ar] = a4.x;
    As[ak + 1][ar] = a4.y;
    As[ak + 2][ar] = a4.z;
    As[ak + 3][ar] = a4.w;
    *reinterpret_cast<float4*>(&Bs[bk][bn]) = b4;
    __syncthreads();
#pragma unroll
    for (int kk = 0; kk < 8; ++kk) {
      float4 a0 = *reinterpret_cast<const float4*>(&As[kk][ty * 8]);
      float4 a1 = *reinterpret_cast<const float4*>(&As[kk][ty * 8 + 4]);
      float4 b0 = *reinterpret_cast<const float4*>(&Bs[kk][tx * 8]);
      float4 b1 = *reinterpret_cast<const float4*>(&Bs[kk][tx * 8 + 4]);
      float av[8] = {a0.x, a0.y, a0.z, a0.w, a1.x, a1.y, a1.z, a1.w};
      float bv[8] = {b0.x, b0.y, b0.z, b0.w, b1.x, b1.y, b1.z, b1.w};
#pragma unroll
      for (int i = 0; i < 8; ++i)
#pragma unroll
        for (int j = 0; j < 8; ++j) acc[i][j] += av[i] * bv[j];
    }
  }
#pragma unroll
  for (int i = 0; i < 8; ++i) {
    int row = r0 + ty * 8 + i;
#pragma unroll
    for (int j0 = 0; j0 < 8; j0 += 4) {
      float4 o = make_float4(acc[i][j0 + 0] * scale, acc[i][j0 + 1] * scale,
                             acc[i][j0 + 2] * scale, acc[i][j0 + 3] * scale);
      *reinterpret_cast<float4*>(&O[row * 1024 + c0 + tx * 8 + j0]) = o;
    }
  }
}

// ---------------------------------------------------------------------------
// Output projection, same 128-tile shape. grid (rows/128, 8).
// ---------------------------------------------------------------------------
__global__ __launch_bounds__(256) void gemm_out(
    const float* __restrict__ Og, const float* __restrict__ Wo,
    float* __restrict__ out, int tg, int lsh)
{
  const int r0 = blockIdx.x * 128;
  const int c0 = blockIdx.y * 128;
  const int tid = threadIdx.x;
  const int tx = tid & 15, ty = tid >> 4;

  __shared__ float As[8][132];
  __shared__ float Bs[8][132];

  float acc[8][8] = {};
  const int ar = tid >> 1;
  const int ak = (tid & 1) * 4;
  const int bk = tid >> 5;
  const int bn = (tid & 31) * 4;

  for (int k0 = 0; k0 < 1024; k0 += 8) {
    float4 a4 = *reinterpret_cast<const float4*>(&Og[(r0 + ar) * 1024 + k0 + ak]);
    float4 b4 = *reinterpret_cast<const float4*>(&Wo[(k0 + bk) * 1024 + c0 + bn]);
    __syncthreads();
    As[ak + 0][ar] = a4.x;
    As[ak + 1][ar] = a4.y;
    As[ak + 2][ar] = a4.z;
    As[ak + 3][ar] = a4.w;
    *reinterpret_cast<float4*>(&Bs[bk][bn]) = b4;
    __syncthreads();
#pragma unroll
    for (int kk = 0; kk < 8; ++kk) {
      float4 a0 = *reinterpret_cast<const float4*>(&As[kk][ty * 8]);
      float4 a1 = *reinterpret_cast<const float4*>(&As[kk][ty * 8 + 4]);
      float4 b0 = *reinterpret_cast<const float4*>(&Bs[kk][tx * 8]);
      float4 b1 = *reinterpret_cast<const float4*>(&Bs[kk][tx * 8 + 4]);
      float av[8] = {a0.x, a0.y, a0.z, a0.w, a1.x, a1.y, a1.z, a1.w};
      float bv[8] = {b0.x, b0.y, b0.z, b0.w, b1.x, b1.y, b1.z, b1.w};
#pragma unroll
      for (int i = 0; i < 8; ++i)
#pragma unroll
        for (int j = 0; j < 8; ++j) acc[i][j] += av[i] * bv[j];
    }
  }
#pragma unroll
  for (int i = 0; i < 8; ++i) {
    int lr = r0 + ty * 8 + i;
    int grow = ((lr >> lsh) << 11) + tg + (lr & ((1 << lsh) - 1));
#pragma unroll
    for (int j0 = 0; j0 < 8; j0 += 4) {
      float4 o = make_float4(acc[i][j0], acc[i][j0 + 1], acc[i][j0 + 2], acc[i][j0 + 3]);
      *reinterpret_cast<float4*>(&out[grow * 1024 + c0 + tx * 8 + j0]) = o;
    }
  }
}

// ---------------------------------------------------------------------------
// Row-normalize Kg (rows x 1024)
// ---------------------------------------------------------------------------
__global__ __launch_bounds__(256) void knorm_kernel(float* __restrict__ K) {
  const int row = blockIdx.x;
  const int tid = threadIdx.x;
  float4 v4 = *reinterpret_cast<const float4*>(&K[row * 1024 + tid * 4]);
  float ss = v4.x * v4.x + v4.y * v4.y + v4.z * v4.z + v4.w * v4.w;
#pragma unroll
  for (int off = 32; off > 0; off >>= 1) ss += __shfl_down(ss, off);
  __shared__ float wsum[4];
  if ((tid & 63) == 0) wsum[tid >> 6] = ss;
  __syncthreads();
  float tot = wsum[0] + wsum[1] + wsum[2] + wsum[3];
  float inv = 1.0f / fmaxf(sqrtf(tot), 1e-12f);
  float4 o = make_float4(v4.x * inv, v4.y * inv, v4.z * inv, v4.w * inv);
  *reinterpret_cast<float4*>(&K[row * 1024 + tid * 4]) = o;
}

// ---------------------------------------------------------------------------
// A/P precompute. z=0: A=strict-tril(KK^T); z=1: P=tril(QK^T). grid (2,B_,cpg)
// ---------------------------------------------------------------------------
__global__ __launch_bounds__(256) void attn_all_kernel(
    const float* __restrict__ Q, const float* __restrict__ K,
    float* __restrict__ Ag, float* __restrict__ Pg, int tgs)
{
  const int z = blockIdx.x;
  const int b = blockIdx.y;
  const int cc = blockIdx.z;
  const int base = b * tgs + cc * CH;
  const float* R = z ? Q : K;
  const int tid = threadIdx.x;
  const int tx = tid & 15, ty = tid >> 4;
  __shared__ float Rs[64][68];
  __shared__ float Cs[64][68];
  float acc[4][4] = {};
  for (int d0 = 0; d0 < 1024; d0 += 64) {
    __syncthreads();
#pragma unroll
    for (int i = 0; i < 4; ++i) {
      int qq = tid + i * 256;
      int t = qq >> 4, dq = (qq & 15) * 4;
      int gidx = (base + t) * 1024 + d0 + dq;
      *reinterpret_cast<float4*>(&Rs[t][dq]) = *reinterpret_cast<const float4*>(&R[gidx]);
      *reinterpret_cast<float4*>(&Cs[t][dq]) = *reinterpret_cast<const float4*>(&K[gidx]);
    }
    __syncthreads();
#pragma unroll
    for (int dd = 0; dd < 64; dd += 4) {
      float4 rv[4], cv[4];
#pragma unroll
      for (int a = 0; a < 4; ++a) rv[a] = *reinterpret_cast<const float4*>(&Rs[ty * 4 + a][dd]);
#pragma unroll
      for (int bb = 0; bb < 4; ++bb) cv[bb] = *reinterpret_cast<const float4*>(&Cs[tx * 4 + bb][dd]);
#pragma unroll
      for (int a = 0; a < 4; ++a)
#pragma unroll
        for (int bb = 0; bb < 4; ++bb)
          acc[a][bb] += rv[a].x * cv[bb].x + rv[a].y * cv[bb].y +
                        rv[a].z * cv[bb].z + rv[a].w * cv[bb].w;
    }
  }
  float* Out = z ? Pg : Ag;
#pragma unroll
  for (int a = 0; a < 4; ++a) {
    int t = ty * 4 + a;
    float4 o;
    int i0 = tx * 4;
    if (z == 0) {
      o.x = (i0 + 0 < t) ? acc[a][0] : 0.0f; o.y = (i0 + 1 < t) ? acc[a][1] : 0.0f;
      o.z = (i0 + 2 < t) ? acc[a][2] : 0.0f; o.w = (i0 + 3 < t) ? acc[a][3] : 0.0f;
    } else {
      o.x = (i0 + 0 <= t) ? acc[a][0] : 0.0f; o.y = (i0 + 1 <= t) ? acc[a][1] : 0.0f;
      o.z = (i0 + 2 <= t) ? acc[a][2] : 0.0f; o.w = (i0 + 3 <= t) ? acc[a][3] : 0.0f;
    }
    *reinterpret_cast<float4*>(&Out[((cc * B_ + b) * CH + t) * 64 + i0]) = o;
  }
}

// ---------------------------------------------------------------------------
// Persistent-state chain. 256 wgs; wg = b*NSL + sl owns S[c0:c0+16][0:1024]
// in LDS for the whole kernel. K/Q are read DIRECTLY from global (L2-resident:
// 512 KB per chunk per XCD) — 16 lanes/wave share each address (HW coalesce).
// This keeps the LDS pipe for S/u/A/P only (round-7 was ds_read-throughput
// bound at 9 LDS reads per 32 FMA). Per chunk: phase A (KS/QS dot-products),
// phase B (column-local triangular solve), phase C (rank-64 S update).
// No inter-wg communication at all.
// ---------------------------------------------------------------------------
__global__ __launch_bounds__(256) void chain_kernel(
    const float* __restrict__ Qf, const float* __restrict__ Kf,
    const float* __restrict__ Vf, float* __restrict__ Of,
    const float* __restrict__ Ag, const float* __restrict__ Pg,
    float* __restrict__ Sglob, int lsh, int cpg, int g, int ngrp)
{
  const int wg = blockIdx.x;
  const int b = wg >> 6;
  const int sl = wg & 63;
  const int c0 = sl * SLW;
  const int tgs = 1 << lsh;
  const int tid = threadIdx.x;
  const int c = tid & 15;        // column within slice
  const int tg = tid >> 4;       // t-group of 4 (phase A) / d-group (phase C)

  __shared__ float Ssl[SLW][1028];   // persistent S slice
  __shared__ float Asm[64][64];
  __shared__ float Psm[64][64];
  __shared__ float uT[SLW][68];      // u transposed [c][t]
  __shared__ float rhs[64][SLW];
  __shared__ float qsa[64][SLW];

  // init S slice
  if (g == 0) {
#pragma unroll
    for (int i = 0; i < 16; ++i) {
      int idx = tid + i * 256;
      int r = idx >> 8, d4 = (idx & 255) * 4;
      *reinterpret_cast<float4*>(&Ssl[r][d4]) = make_float4(0.f, 0.f, 0.f, 0.f);
    }
  } else {
#pragma unroll
    for (int i = 0; i < 16; ++i) {
      int idx = tid + i * 256;
      int r = idx >> 8, d4 = (idx & 255) * 4;
      *reinterpret_cast<float4*>(&Ssl[r][d4]) =
          *reinterpret_cast<const float4*>(&Sglob[((size_t)b * 1024 + c0 + r) * 1024 + d4]);
    }
  }
  __syncthreads();

  for (int cc = 0; cc < cpg; ++cc) {
    const int base = b * tgs + cc * CH;
    const int abase = ((cc * B_ + b) * CH) * 64;
    const float* Kc = &Kf[(size_t)base * 1024];
    const float* Qc = &Qf[(size_t)base * 1024];

    // ---- phase A: KS/QS over full d; K/Q from global, S from LDS ----
    {
      float accK[4] = {0.f, 0.f, 0.f, 0.f};
      float accQ[4] = {0.f, 0.f, 0.f, 0.f};
      const float* k0p = &Kc[(tg * 4 + 0) * 1024];
      const float* k1p = &Kc[(tg * 4 + 1) * 1024];
      const float* k2p = &Kc[(tg * 4 + 2) * 1024];
      const float* k3p = &Kc[(tg * 4 + 3) * 1024];
      const float* q0p = &Qc[(tg * 4 + 0) * 1024];
      const float* q1p = &Qc[(tg * 4 + 1) * 1024];
      const float* q2p = &Qc[(tg * 4 + 2) * 1024];
      const float* q3p = &Qc[(tg * 4 + 3) * 1024];
      for (int d0 = 0; d0 < 1024; d0 += 8) {
        float4 sa = *reinterpret_cast<const float4*>(&Ssl[c][d0]);
        float4 sb = *reinterpret_cast<const float4*>(&Ssl[c][d0 + 4]);
        float4 ka0 = *reinterpret_cast<const float4*>(&k0p[d0]);
        float4 ka1 = *reinterpret_cast<const float4*>(&k1p[d0]);
        float4 ka2 = *reinterpret_cast<const float4*>(&k2p[d0]);
        float4 ka3 = *reinterpret_cast<const float4*>(&k3p[d0]);
        float4 kb0 = *reinterpret_cast<const float4*>(&k0p[d0 + 4]);
        float4 kb1 = *reinterpret_cast<const float4*>(&k1p[d0 + 4]);
        float4 kb2 = *reinterpret_cast<const float4*>(&k2p[d0 + 4]);
        float4 kb3 = *reinterpret_cast<const float4*>(&k3p[d0 + 4]);
        float4 qa0 = *reinterpret_cast<const float4*>(&q0p[d0]);
        float4 qa1 = *reinterpret_cast<const float4*>(&q1p[d0]);
        float4 qa2 = *reinterpret_cast<const float4*>(&q2p[d0]);
        float4 qa3 = *reinterpret_cast<const float4*>(&q3p[d0]);
        float4 qb0 = *reinterpret_cast<const float4*>(&q0p[d0 + 4]);
        float4 qb1 = *reinterpret_cast<const float4*>(&q1p[d0 + 4]);
        float4 qb2 = *reinterpret_cast<const float4*>(&q2p[d0 + 4]);
        float4 qb3 = *reinterpret_cast<const float4*>(&q3p[d0 + 4]);
        accK[0] += ka0.x*sa.x + ka0.y*sa.y + ka0.z*sa.z + ka0.w*sa.w
                 + kb0.x*sb.x + kb0.y*sb.y + kb0.z*sb.z + kb0.w*sb.w;
        accK[1] += ka1.x*sa.x + ka1.y*sa.y + ka1.z*sa.z + ka1.w*sa.w
                 + kb1.x*sb.x + kb1.y*sb.y + kb1.z*sb.z + kb1.w*sb.w;
        accK[2] += ka2.x*sa.x + ka2.y*sa.y + ka2.z*sa.z + ka2.w*sa.w
                 + kb2.x*sb.x + kb2.y*sb.y + kb2.z*sb.z + kb2.w*sb.w;
        accK[3] += ka3.x*sa.x + ka3.y*sa.y + ka3.z*sa.z + ka3.w*sa.w
                 + kb3.x*sb.x + kb3.y*sb.y + kb3.z*sb.z + kb3.w*sb.w;
        accQ[0] += qa0.x*sa.x + qa0.y*sa.y + qa0.z*sa.z + qa0.w*sa.w
                 + qb0.x*sb.x + qb0.y*sb.y + qb0.z*sb.z + qb0.w*sb.w;
        accQ[1] += qa1.x*sa.x + qa1.y*sa.y + qa1.z*sa.z + qa1.w*sa.w
                 + qb1.x*sb.x + qb1.y*sb.y + qb1.z*sb.z + qb1.w*sb.w;
        accQ[2] += qa2.x*sa.x + qa2.y*sa.y + qa2.z*sa.z + qa2.w*sa.w
                 + qb2.x*sb.x + qb2.y*sb.y + qb2.z*sb.z + qb2.w*sb.w;
        accQ[3] += qa3.x*sa.x + qa3.y*sa.y + qa3.z*sa.z + qa3.w*sa.w
                 + qb3.x*sb.x + qb3.y*sb.y + qb3.z*sb.z + qb3.w*sb.w;
      }
#pragma unroll
      for (int r = 0; r < 4; ++r) {
        int t = tg * 4 + r;
        rhs[t][c] = Vf[(size_t)(base + t) * 1024 + c0 + c] - accK[r];
        qsa[t][c] = accQ[r];
      }
    }
    // stage A, P into LDS
#pragma unroll
    for (int i = 0; i < 4; ++i) {
      int idx = tid + i * 256;
      int row = idx >> 4, i4 = (idx & 15) * 4;
      *reinterpret_cast<float4*>(&Asm[row][i4]) =
          *reinterpret_cast<const float4*>(&Ag[abase + row * 64 + i4]);
      *reinterpret_cast<float4*>(&Psm[row][i4]) =
          *reinterpret_cast<const float4*>(&Pg[abase + row * 64 + i4]);
    }
    __syncthreads();

    // ---- phase B: column-local triangular solve + output ----
    if (tid < SLW) {
      const int cB = tid;
      float uu[64];
#pragma unroll
      for (int t = 0; t < 64; ++t) {
        float x = rhs[t][cB];
        float s0 = 0.f, s1 = 0.f, s2 = 0.f, s3 = 0.f;
        for (int i0 = 0; i0 + 4 <= t; i0 += 4) {
          float4 a4 = *reinterpret_cast<const float4*>(&Asm[t][i0]);
          s0 += a4.x * uu[i0 + 0]; s1 += a4.y * uu[i0 + 1];
          s2 += a4.z * uu[i0 + 2]; s3 += a4.w * uu[i0 + 3];
        }
        for (int i = (t >> 2) << 2; i < t; ++i) s0 += Asm[t][i] * uu[i];
        uu[t] = x - ((s0 + s1) + (s2 + s3));
        uT[cB][t] = uu[t];
      }
#pragma unroll
      for (int t = 0; t < 64; ++t) {
        float o = qsa[t][cB];
        float s0 = 0.f, s1 = 0.f, s2 = 0.f, s3 = 0.f;
        for (int i0 = 0; i0 + 4 <= t + 1; i0 += 4) {
          float4 p4 = *reinterpret_cast<const float4*>(&Psm[t][i0]);
          s0 += p4.x * uu[i0 + 0]; s1 += p4.y * uu[i0 + 1];
          s2 += p4.z * uu[i0 + 2]; s3 += p4.w * uu[i0 + 3];
        }
        for (int i = ((t + 1) >> 2) << 2; i <= t; ++i) s0 += Psm[t][i] * uu[i];
        qsa[t][cB] = o + (s0 + s1) + (s2 + s3);
      }
    }
    __syncthreads();

    // write O tile (coalesced float4)
    {
      int row = tid >> 2, c4 = (tid & 3) * 4;
      float4 o4 = make_float4(qsa[row][c4 + 0], qsa[row][c4 + 1],
                              qsa[row][c4 + 2], qsa[row][c4 + 3]);
      *reinterpret_cast<float4*>(&Of[(size_t)(base + row) * 1024 + c0 + c4]) = o4;
    }

    // ---- phase C: S_c += u^T K ; K from global, S/u from LDS ----
    {
      const int dgr = tg;              // 0..15, 4-d block within each 64-block
      for (int d0 = 0; d0 < 1024; d0 += 64) {
        const int d = d0 + dgr * 4;
        float4 s4 = *reinterpret_cast<const float4*>(&Ssl[c][d]);
#pragma unroll 4
        for (int t = 0; t < 64; t += 4) {
          float4 u4 = *reinterpret_cast<const float4*>(&uT[c][t]);
          float4 k0 = *reinterpret_cast<const float4*>(&Kc[(size_t)(t + 0) * 1024 + d]);
          float4 k1 = *reinterpret_cast<const float4*>(&Kc[(size_t)(t + 1) * 1024 + d]);
          float4 k2 = *reinterpret_cast<const float4*>(&Kc[(size_t)(t + 2) * 1024 + d]);
          float4 k3 = *reinterpret_cast<const float4*>(&Kc[(size_t)(t + 3) * 1024 + d]);
          s4.x += u4.x * k0.x + u4.y * k1.x + u4.z * k2.x + u4.w * k3.x;
          s4.y += u4.x * k0.y + u4.y * k1.y + u4.z * k2.y + u4.w * k3.y;
          s4.z += u4.x * k0.z + u4.y * k1.z + u4.z * k2.z + u4.w * k3.z;
          s4.w += u4.x * k0.w + u4.y * k1.w + u4.z * k2.w + u4.w * k3.w;
        }
        *reinterpret_cast<float4*>(&Ssl[c][d]) = s4;
      }
    }
    __syncthreads();
  }

  // spill S slice for next group (ngrp==1 at the full tier: skipped)
  if (g < ngrp - 1) {
#pragma unroll
    for (int i = 0; i < 16; ++i) {
      int idx = tid + i * 256;
      int r = idx >> 8, d4 = (idx & 255) * 4;
      *reinterpret_cast<float4*>(&Sglob[((size_t)b * 1024 + c0 + r) * 1024 + d4]) =
          *reinterpret_cast<const float4*>(&Ssl[r][d4]);
    }
  }
}

// ---------------------------------------------------------------------------
extern "C" void kernel_launch(void* const* d_in, const int* in_sizes, int n_in,
                              void* d_out, int out_size, void* d_ws, size_t ws_size,
                              hipStream_t stream) {
  const float* x  = (const float*)d_in[0];
  const float* Wq = (const float*)d_in[1];
  const float* Wk = (const float*)d_in[2];
  const float* Wv = (const float*)d_in[3];
  const float* Wo = (const float*)d_in[4];
  float* out = (float*)d_out;

  // tier: largest time-group that fits ws
  int lsh = 8;
  {
    const int cand[4] = {11, 10, 9, 8};
    for (int i = 0; i < 4; ++i) {
      size_t tgs = (size_t)1 << cand[i];
      size_t cpg = tgs / CH;
      size_t need = 4 * (B_ * tgs * 1024 * 4)             // Q,K,V,O
                  + 2 * (cpg * B_ * CH * 64 * 4)          // A,P
                  + (size_t)B_ * 1024 * 1024 * 4          // Sglob
                  + 16384;
      if (need <= ws_size) { lsh = cand[i]; break; }
    }
  }
  const int tgs = 1 << lsh;
  const int cpg = tgs / CH;
  const int ngrp = T_ / tgs;
  const int rows = B_ * tgs;

  char* ws = (char*)d_ws;
  size_t off = 0;
  auto alloc = [&](size_t bytes) -> void* {
    void* p = ws + off;
    off += (bytes + 255) & ~(size_t)255;
    return p;
  };
  float* Qg = (float*)alloc((size_t)rows * 1024 * 4);
  float* Kg = (float*)alloc((size_t)rows * 1024 * 4);
  float* Vg = (float*)alloc((size_t)rows * 1024 * 4);
  float* Og = (float*)alloc((size_t)rows * 1024 * 4);
  float* Ag = (float*)alloc((size_t)cpg * B_ * CH * 64 * 4);
  float* Pg = (float*)alloc((size_t)cpg * B_ * CH * 64 * 4);
  float* Sglob = (float*)alloc((size_t)B_ * 1024 * 1024 * 4);

  for (int g = 0; g < ngrp; ++g) {
    int tg = g * tgs;
    gemm_qkv<<<dim3(rows / 128, 8, 3), 256, 0, stream>>>(x, Wq, Wk, Wv, Qg, Kg, Vg, tg, lsh);
    knorm_kernel<<<rows, 256, 0, stream>>>(Kg);
    attn_all_kernel<<<dim3(2, B_, cpg), 256, 0, stream>>>(Qg, Kg, Ag, Pg, tgs);
    chain_kernel<<<256, 256, 0, stream>>>(Qg, Kg, Vg, Og, Ag, Pg, Sglob, lsh, cpg, g, ngrp);
    gemm_out<<<dim3(rows / 128, 8), 256, 0, stream>>>(Og, Wo, out, tg, lsh);
  }
}

// Round 9
// 1324.955 us; speedup vs baseline: 4.8816x; 4.8816x over previous
//
#include <hip/hip_runtime.h>

typedef unsigned short u16;
typedef __attribute__((ext_vector_type(8))) short short8;     // 8 bf16 (4 VGPRs)
typedef __attribute__((ext_vector_type(4))) float floatx4;    // 4 fp32 acc

#define B_ 4
#define T_ 2048
#define CH 64

__device__ __forceinline__ u16 f2bf(float f) {
  unsigned int x = __float_as_uint(f);
  return (u16)((x + 0x7FFFu + ((x >> 16) & 1u)) >> 16);
}

// ---------------------------------------------------------------------------
// QKV projection fp32. z=0 -> Qbf (bf16, scaled 1/32); z=1 -> Kg fp32;
// z=2 -> Vg fp32. 128x128 tile, 8x8 micro, BK=8. grid (rows/128, 8, 3).
// ---------------------------------------------------------------------------
__global__ __launch_bounds__(256) void gemm_qkv(
    const float* __restrict__ X,
    const float* __restrict__ W0, const float* __restrict__ W1, const float* __restrict__ W2,
    u16* __restrict__ Qbf, float* __restrict__ Kg, float* __restrict__ Vg,
    int tg, int lsh)
{
  const int z = blockIdx.z;
  const float* W = (z == 0) ? W0 : ((z == 1) ? W1 : W2);
  const float scale = (z == 0) ? 0.03125f : 1.0f;
  const int r0 = blockIdx.x * 128;
  const int c0 = blockIdx.y * 128;
  const int tid = threadIdx.x;
  const int tx = tid & 15, ty = tid >> 4;

  __shared__ float As[8][132];
  __shared__ float Bs[8][132];

  float acc[8][8] = {};
  const int ar = tid >> 1;
  const int ak = (tid & 1) * 4;
  const int bk = tid >> 5;
  const int bn = (tid & 31) * 4;

  const int lr = r0 + ar;
  const int grow = ((lr >> lsh) << 11) + tg + (lr & ((1 << lsh) - 1));

  for (int k0 = 0; k0 < 1024; k0 += 8) {
    float4 a4 = *reinterpret_cast<const float4*>(&X[grow * 1024 + k0 + ak]);
    float4 b4 = *reinterpret_cast<const float4*>(&W[(k0 + bk) * 1024 + c0 + bn]);
    __syncthreads();
    As[ak + 0][ar] = a4.x;
    As[ak + 1][ar] = a4.y;
    As[ak + 2][ar] = a4.z;
    As[ak + 3][ar] = a4.w;
    *reinterpret_cast<float4*>(&Bs[bk][bn]) = b4;
    __syncthreads();
#pragma unroll
    for (int kk = 0; kk < 8; ++kk) {
      float4 a0 = *reinterpret_cast<const float4*>(&As[kk][ty * 8]);
      float4 a1 = *reinterpret_cast<const float4*>(&As[kk][ty * 8 + 4]);
      float4 b0 = *reinterpret_cast<const float4*>(&Bs[kk][tx * 8]);
      float4 b1 = *reinterpret_cast<const float4*>(&Bs[kk][tx * 8 + 4]);
      float av[8] = {a0.x, a0.y, a0.z, a0.w, a1.x, a1.y, a1.z, a1.w};
      float bv[8] = {b0.x, b0.y, b0.z, b0.w, b1.x, b1.y, b1.z, b1.w};
#pragma unroll
      for (int i = 0; i < 8; ++i)
#pragma unroll
        for (int j = 0; j < 8; ++j) acc[i][j] += av[i] * bv[j];
    }
  }
#pragma unroll
  for (int i = 0; i < 8; ++i) {
    int row = r0 + ty * 8 + i;
    if (z == 0) {
      ushort4 qa, qb;
      qa.x = f2bf(acc[i][0] * scale); qa.y = f2bf(acc[i][1] * scale);
      qa.z = f2bf(acc[i][2] * scale); qa.w = f2bf(acc[i][3] * scale);
      qb.x = f2bf(acc[i][4] * scale); qb.y = f2bf(acc[i][5] * scale);
      qb.z = f2bf(acc[i][6] * scale); qb.w = f2bf(acc[i][7] * scale);
      *reinterpret_cast<ushort4*>(&Qbf[row * 1024 + c0 + tx * 8]) = qa;
      *reinterpret_cast<ushort4*>(&Qbf[row * 1024 + c0 + tx * 8 + 4]) = qb;
    } else {
      float* O = (z == 1) ? Kg : Vg;
#pragma unroll
      for (int j0 = 0; j0 < 8; j0 += 4) {
        float4 o = make_float4(acc[i][j0], acc[i][j0 + 1], acc[i][j0 + 2], acc[i][j0 + 3]);
        *reinterpret_cast<float4*>(&O[row * 1024 + c0 + tx * 8 + j0]) = o;
      }
    }
  }
}

// ---------------------------------------------------------------------------
// Output projection fp32 (reads Of). 128x128 tile. grid (rows/128, 8).
// ---------------------------------------------------------------------------
__global__ __launch_bounds__(256) void gemm_out(
    const float* __restrict__ Og, const float* __restrict__ Wo,
    float* __restrict__ out, int tg, int lsh)
{
  const int r0 = blockIdx.x * 128;
  const int c0 = blockIdx.y * 128;
  const int tid = threadIdx.x;
  const int tx = tid & 15, ty = tid >> 4;

  __shared__ float As[8][132];
  __shared__ float Bs[8][132];

  float acc[8][8] = {};
  const int ar = tid >> 1;
  const int ak = (tid & 1) * 4;
  const int bk = tid >> 5;
  const int bn = (tid & 31) * 4;

  for (int k0 = 0; k0 < 1024; k0 += 8) {
    float4 a4 = *reinterpret_cast<const float4*>(&Og[(r0 + ar) * 1024 + k0 + ak]);
    float4 b4 = *reinterpret_cast<const float4*>(&Wo[(k0 + bk) * 1024 + c0 + bn]);
    __syncthreads();
    As[ak + 0][ar] = a4.x;
    As[ak + 1][ar] = a4.y;
    As[ak + 2][ar] = a4.z;
    As[ak + 3][ar] = a4.w;
    *reinterpret_cast<float4*>(&Bs[bk][bn]) = b4;
    __syncthreads();
#pragma unroll
    for (int kk = 0; kk < 8; ++kk) {
      float4 a0 = *reinterpret_cast<const float4*>(&As[kk][ty * 8]);
      float4 a1 = *reinterpret_cast<const float4*>(&As[kk][ty * 8 + 4]);
      float4 b0 = *reinterpret_cast<const float4*>(&Bs[kk][tx * 8]);
      float4 b1 = *reinterpret_cast<const float4*>(&Bs[kk][tx * 8 + 4]);
      float av[8] = {a0.x, a0.y, a0.z, a0.w, a1.x, a1.y, a1.z, a1.w};
      float bv[8] = {b0.x, b0.y, b0.z, b0.w, b1.x, b1.y, b1.z, b1.w};
#pragma unroll
      for (int i = 0; i < 8; ++i)
#pragma unroll
        for (int j = 0; j < 8; ++j) acc[i][j] += av[i] * bv[j];
    }
  }
#pragma unroll
  for (int i = 0; i < 8; ++i) {
    int lr = r0 + ty * 8 + i;
    int grow = ((lr >> lsh) << 11) + tg + (lr & ((1 << lsh) - 1));
#pragma unroll
    for (int j0 = 0; j0 < 8; j0 += 4) {
      float4 o = make_float4(acc[i][j0], acc[i][j0 + 1], acc[i][j0 + 2], acc[i][j0 + 3]);
      *reinterpret_cast<float4*>(&out[grow * 1024 + c0 + tx * 8 + j0]) = o;
    }
  }
}

// ---------------------------------------------------------------------------
// Row-normalize Kg (fp32) -> Kbf (bf16 row-major)
// ---------------------------------------------------------------------------
__global__ __launch_bounds__(256) void knorm_kernel(const float* __restrict__ K,
                                                    u16* __restrict__ Kbf) {
  const int row = blockIdx.x;
  const int tid = threadIdx.x;
  float4 v4 = *reinterpret_cast<const float4*>(&K[row * 1024 + tid * 4]);
  float ss = v4.x * v4.x + v4.y * v4.y + v4.z * v4.z + v4.w * v4.w;
#pragma unroll
  for (int off = 32; off > 0; off >>= 1) ss += __shfl_down(ss, off);
  __shared__ float wsum[4];
  if ((tid & 63) == 0) wsum[tid >> 6] = ss;
  __syncthreads();
  float tot = wsum[0] + wsum[1] + wsum[2] + wsum[3];
  float inv = 1.0f / fmaxf(sqrtf(tot), 1e-12f);
  ushort4 o;
  o.x = f2bf(v4.x * inv); o.y = f2bf(v4.y * inv);
  o.z = f2bf(v4.z * inv); o.w = f2bf(v4.w * inv);
  *reinterpret_cast<ushort4*>(&Kbf[row * 1024 + tid * 4]) = o;
}

// ---------------------------------------------------------------------------
// Transpose Kbf -> KT[b][d][t_local] (bf16). grid (tgs/64, 16, B_), 256 thr.
// ---------------------------------------------------------------------------
__global__ __launch_bounds__(256) void ktrans_kernel(const u16* __restrict__ Kbf,
                                                     u16* __restrict__ KT,
                                                     int tgs) {
  const int t0 = blockIdx.x * 64;
  const int d0 = blockIdx.y * 64;
  const int b = blockIdx.z;
  const int tid = threadIdx.x;
  __shared__ u16 Tile[64][68];
#pragma unroll
  for (int i = 0; i < 4; ++i) {
    int lin = tid + i * 256;
    int r = lin >> 4, c4 = (lin & 15) * 4;
    *reinterpret_cast<ushort4*>(&Tile[r][c4]) =
        *reinterpret_cast<const ushort4*>(&Kbf[(size_t)(b * tgs + t0 + r) * 1024 + d0 + c4]);
  }
  __syncthreads();
#pragma unroll
  for (int i = 0; i < 4; ++i) {
    int lin = tid + i * 256;
    int r = lin >> 4, c4 = (lin & 15) * 4;   // r: d-within-tile, c4: t-within-tile
    ushort4 o;
    o.x = Tile[c4 + 0][r]; o.y = Tile[c4 + 1][r];
    o.z = Tile[c4 + 2][r]; o.w = Tile[c4 + 3][r];
    *reinterpret_cast<ushort4*>(&KT[((size_t)b * 1024 + d0 + r) * tgs + t0 + c4]) = o;
  }
}

// ---------------------------------------------------------------------------
// Per (chunk cc, batch b): MFMA QK^T/KK^T -> P (incl-tril, bf16 global) and
// A (strict-tril, LDS) -> W = (I+A)^{-1} (forward subst on I) -> bf16 global.
// grid (cpg, B_), 256 threads.
// ---------------------------------------------------------------------------
__global__ __launch_bounds__(256) void attn_winv_kernel(
    const u16* __restrict__ Qbf, const u16* __restrict__ Kbf,
    u16* __restrict__ Pb, u16* __restrict__ Wb, int tgs)
{
  const int cc = blockIdx.x;
  const int b = blockIdx.y;
  const int base = b * tgs + cc * CH;
  const int tid = threadIdx.x;
  const int lane = tid & 63;
  const int wave = tid >> 6;
  const int quad = lane >> 4, l16 = lane & 15;
  const int m0 = wave * 16;

  __shared__ float Asm[64][64];
  __shared__ float Wsm[64][65];

  floatx4 accA[4] = {};
  floatx4 accP[4] = {};
  const u16* arowK = &Kbf[(size_t)(base + m0 + l16) * 1024];
  const u16* arowQ = &Qbf[(size_t)(base + m0 + l16) * 1024];
#pragma unroll 4
  for (int kk = 0; kk < 32; ++kk) {
    short8 aK = *reinterpret_cast<const short8*>(&arowK[kk * 32 + quad * 8]);
    short8 aQ = *reinterpret_cast<const short8*>(&arowQ[kk * 32 + quad * 8]);
#pragma unroll
    for (int nt = 0; nt < 4; ++nt) {
      short8 bK = *reinterpret_cast<const short8*>(
          &Kbf[(size_t)(base + nt * 16 + l16) * 1024 + kk * 32 + quad * 8]);
      accA[nt] = __builtin_amdgcn_mfma_f32_16x16x32_bf16(aK, bK, accA[nt], 0, 0, 0);
      accP[nt] = __builtin_amdgcn_mfma_f32_16x16x32_bf16(aQ, bK, accP[nt], 0, 0, 0);
    }
  }
  const size_t pw0 = ((size_t)(cc * B_ + b) * CH) * 64;
#pragma unroll
  for (int nt = 0; nt < 4; ++nt) {
#pragma unroll
    for (int reg = 0; reg < 4; ++reg) {
      int t = m0 + quad * 4 + reg;
      int i = nt * 16 + l16;
      Asm[t][i] = (i < t) ? accA[nt][reg] : 0.0f;
      Pb[pw0 + (size_t)t * 64 + i] = f2bf((i <= t) ? accP[nt][reg] : 0.0f);
    }
  }
  __syncthreads();

  if (tid < 64) {
    const int j = tid;
    for (int t = 0; t < 64; ++t) {
      float s = (t == j) ? 1.0f : 0.0f;
      for (int i = 0; i < t; ++i) s -= Asm[t][i] * Wsm[i][j];
      Wsm[t][j] = s;
    }
    for (int t = 0; t < 64; ++t)
      Wb[pw0 + (size_t)t * 64 + j] = f2bf(Wsm[t][j]);
  }
}

// ---------------------------------------------------------------------------
// Persistent-state MFMA chain. 256 wgs x 512 threads (8 waves, 2/SIMD).
// wg = b*64 + sl owns S[c0:c0+16][0:1024] (fp32 master + bf16 shadow in LDS).
// Per chunk: KS/QS = [K|Q]*S^T (MFMA, K-waves 0-3 / Q-waves 4-7 by m-tile);
// u = W(V-KS); o = QS + P u; S += u^T K. All mfma_f32_16x16x32_bf16.
// Frag layouts: A/B [idx=lane&15][k=quad*8+j]; C/D col=lane&15,row=quad*4+reg.
// ---------------------------------------------------------------------------
__global__ __launch_bounds__(512) void chain_kernel(
    const u16* __restrict__ Qbf, const u16* __restrict__ Kbf,
    const u16* __restrict__ KT, const float* __restrict__ Vf,
    float* __restrict__ Of, const u16* __restrict__ Wb, const u16* __restrict__ Pb,
    float* __restrict__ Sglob, int lsh, int cpg, int g, int ngrp)
{
  const int wg = blockIdx.x;
  const int b = wg >> 6;
  const int sl = wg & 63;
  const int c0 = sl * 16;
  const int tgs = 1 << lsh;
  const int tid = threadIdx.x;
  const int lane = tid & 63;
  const int wave = tid >> 6;
  const int quad = lane >> 4, l16 = lane & 15;

  __shared__ float Ssl[16][1028];   // fp32 master S slice
  __shared__ u16 Sb[16][1040];      // bf16 shadow (stride 1040 breaks bank stride)
  __shared__ u16 rhsT[16][80];      // (V - KS)^T bf16
  __shared__ u16 uT[16][80];        // u^T bf16

  // ---- init S ----
  if (g == 0) {
    for (int idx = tid; idx < 16 * 1024; idx += 512) {
      int r = idx >> 10, d = idx & 1023;
      Ssl[r][d] = 0.0f;
      Sb[r][d] = 0;
    }
  } else {
    for (int idx = tid; idx < 16 * 1024; idx += 512) {
      int r = idx >> 10, d = idx & 1023;
      float v = Sglob[((size_t)b * 1024 + c0 + r) * 1024 + d];
      Ssl[r][d] = v;
      Sb[r][d] = f2bf(v);
    }
  }
  __syncthreads();

  const bool isK = (wave < 4);
  const int mt = isK ? wave : (wave - 4);
  const int m0 = mt * 16;

  for (int cc = 0; cc < cpg; ++cc) {
    const int base = b * tgs + cc * CH;
    const size_t pw0 = ((size_t)(cc * B_ + b) * CH) * 64;

    // ---- phase A: KS (K-waves) / QS (Q-waves) = X * S^T ----
    floatx4 accS = {};
    {
      const u16* arow = (isK ? Kbf : Qbf) + (size_t)(base + m0 + l16) * 1024;
#pragma unroll 8
      for (int kk = 0; kk < 32; ++kk) {
        short8 a = *reinterpret_cast<const short8*>(&arow[kk * 32 + quad * 8]);
        short8 bs = *reinterpret_cast<const short8*>(&Sb[l16][kk * 32 + quad * 8]);
        accS = __builtin_amdgcn_mfma_f32_16x16x32_bf16(a, bs, accS, 0, 0, 0);
      }
    }

    // ---- rhs = V - KS (K-waves) ----
    if (isK) {
#pragma unroll
      for (int reg = 0; reg < 4; ++reg) {
        int t = m0 + quad * 4 + reg;
        float v = Vf[(size_t)(base + t) * 1024 + c0 + l16];
        rhsT[l16][t] = f2bf(v - accS[reg]);
      }
    }
    __syncthreads();

    // ---- u = W * rhs (K-waves) ----
    if (isK) {
      floatx4 uacc = {};
      const u16* wrow = &Wb[pw0 + (size_t)(m0 + l16) * 64];
#pragma unroll
      for (int kk = 0; kk < 2; ++kk) {
        short8 a = *reinterpret_cast<const short8*>(&wrow[kk * 32 + quad * 8]);
        short8 br = *reinterpret_cast<const short8*>(&rhsT[l16][kk * 32 + quad * 8]);
        uacc = __builtin_amdgcn_mfma_f32_16x16x32_bf16(a, br, uacc, 0, 0, 0);
      }
#pragma unroll
      for (int reg = 0; reg < 4; ++reg)
        uT[l16][m0 + quad * 4 + reg] = f2bf(uacc[reg]);
    }
    __syncthreads();

    // ---- o = QS + P*u (Q-waves) ----
    if (!isK) {
      floatx4 oacc = accS;
      const u16* prow = &Pb[pw0 + (size_t)(m0 + l16) * 64];
#pragma unroll
      for (int kk = 0; kk < 2; ++kk) {
        short8 a = *reinterpret_cast<const short8*>(&prow[kk * 32 + quad * 8]);
        short8 bu = *reinterpret_cast<const short8*>(&uT[l16][kk * 32 + quad * 8]);
        oacc = __builtin_amdgcn_mfma_f32_16x16x32_bf16(a, bu, oacc, 0, 0, 0);
      }
#pragma unroll
      for (int reg = 0; reg < 4; ++reg) {
        int t = m0 + quad * 4 + reg;
        Of[(size_t)(base + t) * 1024 + c0 + l16] = oacc[reg];
      }
    }

    // ---- phase C: S[c][d] += sum_t u^T[c][t] K[t][d]; wave covers 128 d ----
    {
      short8 ua0 = *reinterpret_cast<const short8*>(&uT[l16][quad * 8]);
      short8 ua1 = *reinterpret_cast<const short8*>(&uT[l16][32 + quad * 8]);
      const int d0w = wave * 128;
#pragma unroll
      for (int nt = 0; nt < 8; ++nt) {
        const int dn = d0w + nt * 16;
        const u16* ktrow = &KT[((size_t)b * 1024 + dn + l16) * tgs + cc * CH];
        short8 b0 = *reinterpret_cast<const short8*>(&ktrow[quad * 8]);
        short8 b1 = *reinterpret_cast<const short8*>(&ktrow[32 + quad * 8]);
        floatx4 cf;
        cf[0] = Ssl[quad * 4 + 0][dn + l16];
        cf[1] = Ssl[quad * 4 + 1][dn + l16];
        cf[2] = Ssl[quad * 4 + 2][dn + l16];
        cf[3] = Ssl[quad * 4 + 3][dn + l16];
        cf = __builtin_amdgcn_mfma_f32_16x16x32_bf16(ua0, b0, cf, 0, 0, 0);
        cf = __builtin_amdgcn_mfma_f32_16x16x32_bf16(ua1, b1, cf, 0, 0, 0);
#pragma unroll
        for (int reg = 0; reg < 4; ++reg) {
          Ssl[quad * 4 + reg][dn + l16] = cf[reg];
          Sb[quad * 4 + reg][dn + l16] = f2bf(cf[reg]);
        }
      }
    }
    __syncthreads();
  }

  // spill S for next group
  if (g < ngrp - 1) {
    for (int idx = tid; idx < 16 * 1024; idx += 512) {
      int r = idx >> 10, d = idx & 1023;
      Sglob[((size_t)b * 1024 + c0 + r) * 1024 + d] = Ssl[r][d];
    }
  }
}

// ---------------------------------------------------------------------------
extern "C" void kernel_launch(void* const* d_in, const int* in_sizes, int n_in,
                              void* d_out, int out_size, void* d_ws, size_t ws_size,
                              hipStream_t stream) {
  const float* x  = (const float*)d_in[0];
  const float* Wq = (const float*)d_in[1];
  const float* Wk = (const float*)d_in[2];
  const float* Wv = (const float*)d_in[3];
  const float* Wo = (const float*)d_in[4];
  float* out = (float*)d_out;

  // tier: largest time-group that fits ws. Of aliases Kg (Kg dead after knorm).
  int lsh = 8;
  {
    const int cand[4] = {11, 10, 9, 8};
    for (int i = 0; i < 4; ++i) {
      size_t tgs = (size_t)1 << cand[i];
      size_t C = (size_t)B_ * tgs * 1024;
      size_t cpg = tgs / CH;
      size_t need = C * 4        // Kg / Of (aliased)
                  + C * 4        // Vg
                  + C * 2 * 3    // Qbf, Kbf, KT
                  + 2 * (cpg * B_ * CH * 64 * 2)   // Pb, Wb
                  + (size_t)B_ * 1024 * 1024 * 4   // Sglob
                  + 32768;
      if (need <= ws_size) { lsh = cand[i]; break; }
    }
  }
  const int tgs = 1 << lsh;
  const int cpg = tgs / CH;
  const int ngrp = T_ / tgs;
  const int rows = B_ * tgs;

  char* ws = (char*)d_ws;
  size_t off = 0;
  auto alloc = [&](size_t bytes) -> void* {
    void* p = ws + off;
    off += (bytes + 255) & ~(size_t)255;
    return p;
  };
  float* Kg  = (float*)alloc((size_t)rows * 1024 * 4);   // aliased: Of
  float* Of  = Kg;
  float* Vg  = (float*)alloc((size_t)rows * 1024 * 4);
  u16* Qbf = (u16*)alloc((size_t)rows * 1024 * 2);
  u16* Kbf = (u16*)alloc((size_t)rows * 1024 * 2);
  u16* KT  = (u16*)alloc((size_t)rows * 1024 * 2);
  u16* Pb  = (u16*)alloc((size_t)cpg * B_ * CH * 64 * 2);
  u16* Wb  = (u16*)alloc((size_t)cpg * B_ * CH * 64 * 2);
  float* Sglob = (float*)alloc((size_t)B_ * 1024 * 1024 * 4);

  for (int g = 0; g < ngrp; ++g) {
    int tg = g * tgs;
    gemm_qkv<<<dim3(rows / 128, 8, 3), 256, 0, stream>>>(x, Wq, Wk, Wv, Qbf, Kg, Vg, tg, lsh);
    knorm_kernel<<<rows, 256, 0, stream>>>(Kg, Kbf);
    ktrans_kernel<<<dim3(tgs / 64, 16, B_), 256, 0, stream>>>(Kbf, KT, tgs);
    attn_winv_kernel<<<dim3(cpg, B_), 256, 0, stream>>>(Qbf, Kbf, Pb, Wb, tgs);
    chain_kernel<<<256, 512, 0, stream>>>(Qbf, Kbf, KT, Vg, Of, Wb, Pb, Sglob,
                                          lsh, cpg, g, ngrp);
    gemm_out<<<dim3(rows / 128, 8), 256, 0, stream>>>(Of, Wo, out, tg, lsh);
  }
}

// Round 10
// 647.580 us; speedup vs baseline: 9.9879x; 2.0460x over previous
//
#include <hip/hip_runtime.h>

typedef unsigned short u16;
typedef __attribute__((ext_vector_type(8))) short short8;     // 8 bf16 (4 VGPRs)
typedef __attribute__((ext_vector_type(4))) float floatx4;    // 4 fp32 acc

#define B_ 4
#define T_ 2048
#define CH 64

__device__ __forceinline__ u16 f2bf(float f) {
  unsigned int x = __float_as_uint(f);
  return (u16)((x + 0x7FFFu + ((x >> 16) & 1u)) >> 16);
}
__device__ __forceinline__ float bf2f(u16 u) {
  union { unsigned int i; float f; } v; v.i = ((unsigned int)u) << 16; return v.f;
}

// ---------------------------------------------------------------------------
// x fp32 -> bf16 (full tensor). grid (B_*T_), 256 thr x 4 elems.
// ---------------------------------------------------------------------------
__global__ __launch_bounds__(256) void xconv_kernel(const float* __restrict__ x,
                                                    u16* __restrict__ Xbf) {
  size_t idx = ((size_t)blockIdx.x * 256 + threadIdx.x) * 4;
  float4 v = *reinterpret_cast<const float4*>(&x[idx]);
  ushort4 o;
  o.x = f2bf(v.x); o.y = f2bf(v.y); o.z = f2bf(v.z); o.w = f2bf(v.w);
  *reinterpret_cast<ushort4*>(&Xbf[idx]) = o;
}

// ---------------------------------------------------------------------------
// Weight transpose+convert: T[n][k] = bf16(W[k][n]). grid (16,16,4).
// ---------------------------------------------------------------------------
__global__ __launch_bounds__(256) void wtrans_kernel(
    const float* __restrict__ W0, const float* __restrict__ W1,
    const float* __restrict__ W2, const float* __restrict__ W3,
    u16* __restrict__ T0, u16* __restrict__ T1,
    u16* __restrict__ T2, u16* __restrict__ T3)
{
  const int z = blockIdx.z;
  const float* W = (z == 0) ? W0 : (z == 1) ? W1 : (z == 2) ? W2 : W3;
  u16* T = (z == 0) ? T0 : (z == 1) ? T1 : (z == 2) ? T2 : T3;
  const int k0 = blockIdx.x * 64, n0 = blockIdx.y * 64;
  const int tid = threadIdx.x;
  __shared__ float Tile[64][65];
#pragma unroll
  for (int i = 0; i < 4; ++i) {
    int lin = tid + i * 256;
    int r = lin >> 4, c4 = (lin & 15) * 4;
    *reinterpret_cast<float4*>(&Tile[r][c4]) =
        *reinterpret_cast<const float4*>(&W[(size_t)(k0 + r) * 1024 + n0 + c4]);
  }
  __syncthreads();
#pragma unroll
  for (int i = 0; i < 4; ++i) {
    int lin = tid + i * 256;
    int r = lin >> 4, c4 = (lin & 15) * 4;   // r: n-within, c4: k-within
    ushort4 o;
    o.x = f2bf(Tile[c4 + 0][r]); o.y = f2bf(Tile[c4 + 1][r]);
    o.z = f2bf(Tile[c4 + 2][r]); o.w = f2bf(Tile[c4 + 3][r]);
    *reinterpret_cast<ushort4*>(&T[(size_t)(n0 + r) * 1024 + k0 + c4]) = o;
  }
}

// ---------------------------------------------------------------------------
// MFMA GEMM for QKV: C[lr] = Xbf[grow(lr)] @ BT^T, bf16 out.
// 128x128 tile, 4 waves (2x2), each 4x4 of 16x16x32 MFMA, BK=32.
// grid (rows/128, 8, 3): z -> (WqT->Qbf*1/32, WkT->Kbf, WvT->Vbf).
// ---------------------------------------------------------------------------
__global__ __launch_bounds__(256) void mgemm_qkv(
    const u16* __restrict__ Xbf,
    const u16* __restrict__ WqT, const u16* __restrict__ WkT, const u16* __restrict__ WvT,
    u16* __restrict__ Qbf, u16* __restrict__ Kbf, u16* __restrict__ Vbf,
    int tg, int lsh)
{
  const int z = blockIdx.z;
  const u16* BT = (z == 0) ? WqT : ((z == 1) ? WkT : WvT);
  u16* O = (z == 0) ? Qbf : ((z == 1) ? Kbf : Vbf);
  const float scale = (z == 0) ? 0.03125f : 1.0f;
  const int r0 = blockIdx.x * 128, c0 = blockIdx.y * 128;
  const int tid = threadIdx.x;
  const int lane = tid & 63, wave = tid >> 6;
  const int quad = lane >> 4, l16 = lane & 15;
  const int wr = (wave >> 1) * 64, wc = (wave & 1) * 64;

  __shared__ u16 As[128][40];
  __shared__ u16 Bs[128][40];

  const int ar = tid >> 1, ac = (tid & 1) * 16;
  const int lr = r0 + ar;
  const int agrow = ((lr >> lsh) << 11) + tg + (lr & ((1 << lsh) - 1));
  const u16* aptr = &Xbf[(size_t)agrow * 1024 + ac];
  const u16* bptr = &BT[(size_t)(c0 + ar) * 1024 + ac];

  floatx4 acc[4][4] = {};
  for (int k0 = 0; k0 < 1024; k0 += 32) {
    float4 av0 = *reinterpret_cast<const float4*>(aptr + k0);
    float4 av1 = *reinterpret_cast<const float4*>(aptr + k0 + 8);
    float4 bv0 = *reinterpret_cast<const float4*>(bptr + k0);
    float4 bv1 = *reinterpret_cast<const float4*>(bptr + k0 + 8);
    __syncthreads();
    *reinterpret_cast<float4*>(&As[ar][ac]) = av0;
    *reinterpret_cast<float4*>(&As[ar][ac + 8]) = av1;
    *reinterpret_cast<float4*>(&Bs[ar][ac]) = bv0;
    *reinterpret_cast<float4*>(&Bs[ar][ac + 8]) = bv1;
    __syncthreads();
    short8 afr[4], bfr[4];
#pragma unroll
    for (int i = 0; i < 4; ++i) {
      afr[i] = *reinterpret_cast<const short8*>(&As[wr + i * 16 + l16][quad * 8]);
      bfr[i] = *reinterpret_cast<const short8*>(&Bs[wc + i * 16 + l16][quad * 8]);
    }
#pragma unroll
    for (int mi = 0; mi < 4; ++mi)
#pragma unroll
      for (int ni = 0; ni < 4; ++ni)
        acc[mi][ni] = __builtin_amdgcn_mfma_f32_16x16x32_bf16(afr[mi], bfr[ni], acc[mi][ni], 0, 0, 0);
  }
#pragma unroll
  for (int mi = 0; mi < 4; ++mi)
#pragma unroll
    for (int reg = 0; reg < 4; ++reg) {
      int row = r0 + wr + mi * 16 + quad * 4 + reg;
#pragma unroll
      for (int ni = 0; ni < 4; ++ni) {
        int col = c0 + wc + ni * 16 + l16;
        O[(size_t)row * 1024 + col] = f2bf(acc[mi][ni][reg] * scale);
      }
    }
}

// ---------------------------------------------------------------------------
// MFMA GEMM out-proj: out[grow(lr)] = Obf[lr] @ WoT^T, fp32 out. grid (rows/128, 8)
// ---------------------------------------------------------------------------
__global__ __launch_bounds__(256) void mgemm_out(
    const u16* __restrict__ Obf, const u16* __restrict__ WoT,
    float* __restrict__ out, int tg, int lsh)
{
  const int r0 = blockIdx.x * 128, c0 = blockIdx.y * 128;
  const int tid = threadIdx.x;
  const int lane = tid & 63, wave = tid >> 6;
  const int quad = lane >> 4, l16 = lane & 15;
  const int wr = (wave >> 1) * 64, wc = (wave & 1) * 64;

  __shared__ u16 As[128][40];
  __shared__ u16 Bs[128][40];

  const int ar = tid >> 1, ac = (tid & 1) * 16;
  const u16* aptr = &Obf[(size_t)(r0 + ar) * 1024 + ac];
  const u16* bptr = &WoT[(size_t)(c0 + ar) * 1024 + ac];

  floatx4 acc[4][4] = {};
  for (int k0 = 0; k0 < 1024; k0 += 32) {
    float4 av0 = *reinterpret_cast<const float4*>(aptr + k0);
    float4 av1 = *reinterpret_cast<const float4*>(aptr + k0 + 8);
    float4 bv0 = *reinterpret_cast<const float4*>(bptr + k0);
    float4 bv1 = *reinterpret_cast<const float4*>(bptr + k0 + 8);
    __syncthreads();
    *reinterpret_cast<float4*>(&As[ar][ac]) = av0;
    *reinterpret_cast<float4*>(&As[ar][ac + 8]) = av1;
    *reinterpret_cast<float4*>(&Bs[ar][ac]) = bv0;
    *reinterpret_cast<float4*>(&Bs[ar][ac + 8]) = bv1;
    __syncthreads();
    short8 afr[4], bfr[4];
#pragma unroll
    for (int i = 0; i < 4; ++i) {
      afr[i] = *reinterpret_cast<const short8*>(&As[wr + i * 16 + l16][quad * 8]);
      bfr[i] = *reinterpret_cast<const short8*>(&Bs[wc + i * 16 + l16][quad * 8]);
    }
#pragma unroll
    for (int mi = 0; mi < 4; ++mi)
#pragma unroll
      for (int ni = 0; ni < 4; ++ni)
        acc[mi][ni] = __builtin_amdgcn_mfma_f32_16x16x32_bf16(afr[mi], bfr[ni], acc[mi][ni], 0, 0, 0);
  }
#pragma unroll
  for (int mi = 0; mi < 4; ++mi)
#pragma unroll
    for (int reg = 0; reg < 4; ++reg) {
      int lr = r0 + wr + mi * 16 + quad * 4 + reg;
      int grow = ((lr >> lsh) << 11) + tg + (lr & ((1 << lsh) - 1));
#pragma unroll
      for (int ni = 0; ni < 4; ++ni) {
        int col = c0 + wc + ni * 16 + l16;
        out[(size_t)grow * 1024 + col] = acc[mi][ni][reg];
      }
    }
}

// ---------------------------------------------------------------------------
// Row-normalize Kbf in place (bf16, fp32 math). grid (rows).
// ---------------------------------------------------------------------------
__global__ __launch_bounds__(256) void knorm_kernel(u16* __restrict__ Kbf) {
  const int row = blockIdx.x;
  const int tid = threadIdx.x;
  ushort4 v4 = *reinterpret_cast<const ushort4*>(&Kbf[(size_t)row * 1024 + tid * 4]);
  float a = bf2f(v4.x), b = bf2f(v4.y), c = bf2f(v4.z), d = bf2f(v4.w);
  float ss = a * a + b * b + c * c + d * d;
#pragma unroll
  for (int off = 32; off > 0; off >>= 1) ss += __shfl_down(ss, off);
  __shared__ float wsum[4];
  if ((tid & 63) == 0) wsum[tid >> 6] = ss;
  __syncthreads();
  float tot = wsum[0] + wsum[1] + wsum[2] + wsum[3];
  float inv = 1.0f / fmaxf(sqrtf(tot), 1e-12f);
  ushort4 o;
  o.x = f2bf(a * inv); o.y = f2bf(b * inv); o.z = f2bf(c * inv); o.w = f2bf(d * inv);
  *reinterpret_cast<ushort4*>(&Kbf[(size_t)row * 1024 + tid * 4]) = o;
}

// ---------------------------------------------------------------------------
// Transpose Kbf -> KT[b][d][t_local] (bf16). grid (tgs/64, 16, B_), 256 thr.
// ---------------------------------------------------------------------------
__global__ __launch_bounds__(256) void ktrans_kernel(const u16* __restrict__ Kbf,
                                                     u16* __restrict__ KT,
                                                     int tgs) {
  const int t0 = blockIdx.x * 64;
  const int d0 = blockIdx.y * 64;
  const int b = blockIdx.z;
  const int tid = threadIdx.x;
  __shared__ u16 Tile[64][68];
#pragma unroll
  for (int i = 0; i < 4; ++i) {
    int lin = tid + i * 256;
    int r = lin >> 4, c4 = (lin & 15) * 4;
    *reinterpret_cast<ushort4*>(&Tile[r][c4]) =
        *reinterpret_cast<const ushort4*>(&Kbf[(size_t)(b * tgs + t0 + r) * 1024 + d0 + c4]);
  }
  __syncthreads();
#pragma unroll
  for (int i = 0; i < 4; ++i) {
    int lin = tid + i * 256;
    int r = lin >> 4, c4 = (lin & 15) * 4;
    ushort4 o;
    o.x = Tile[c4 + 0][r]; o.y = Tile[c4 + 1][r];
    o.z = Tile[c4 + 2][r]; o.w = Tile[c4 + 3][r];
    *reinterpret_cast<ushort4*>(&KT[((size_t)b * 1024 + d0 + r) * tgs + t0 + c4]) = o;
  }
}

// ---------------------------------------------------------------------------
// Per (chunk, batch): MFMA QK^T/KK^T -> P (incl-tril, bf16) and A (strict-tril)
// -> W = (I+A)^{-1} (forward subst) -> bf16. grid (cpg, B_), 256 threads.
// ---------------------------------------------------------------------------
__global__ __launch_bounds__(256) void attn_winv_kernel(
    const u16* __restrict__ Qbf, const u16* __restrict__ Kbf,
    u16* __restrict__ Pb, u16* __restrict__ Wb, int tgs)
{
  const int cc = blockIdx.x;
  const int b = blockIdx.y;
  const int base = b * tgs + cc * CH;
  const int tid = threadIdx.x;
  const int lane = tid & 63;
  const int wave = tid >> 6;
  const int quad = lane >> 4, l16 = lane & 15;
  const int m0 = wave * 16;

  __shared__ float Asm[64][64];
  __shared__ float Wsm[64][65];

  floatx4 accA[4] = {};
  floatx4 accP[4] = {};
  const u16* arowK = &Kbf[(size_t)(base + m0 + l16) * 1024];
  const u16* arowQ = &Qbf[(size_t)(base + m0 + l16) * 1024];
#pragma unroll 4
  for (int kk = 0; kk < 32; ++kk) {
    short8 aK = *reinterpret_cast<const short8*>(&arowK[kk * 32 + quad * 8]);
    short8 aQ = *reinterpret_cast<const short8*>(&arowQ[kk * 32 + quad * 8]);
#pragma unroll
    for (int nt = 0; nt < 4; ++nt) {
      short8 bK = *reinterpret_cast<const short8*>(
          &Kbf[(size_t)(base + nt * 16 + l16) * 1024 + kk * 32 + quad * 8]);
      accA[nt] = __builtin_amdgcn_mfma_f32_16x16x32_bf16(aK, bK, accA[nt], 0, 0, 0);
      accP[nt] = __builtin_amdgcn_mfma_f32_16x16x32_bf16(aQ, bK, accP[nt], 0, 0, 0);
    }
  }
  const size_t pw0 = ((size_t)(cc * B_ + b) * CH) * 64;
#pragma unroll
  for (int nt = 0; nt < 4; ++nt) {
#pragma unroll
    for (int reg = 0; reg < 4; ++reg) {
      int t = m0 + quad * 4 + reg;
      int i = nt * 16 + l16;
      Asm[t][i] = (i < t) ? accA[nt][reg] : 0.0f;
      Pb[pw0 + (size_t)t * 64 + i] = f2bf((i <= t) ? accP[nt][reg] : 0.0f);
    }
  }
  __syncthreads();

  if (tid < 64) {
    const int j = tid;
    for (int t = 0; t < 64; ++t) {
      float s = (t == j) ? 1.0f : 0.0f;
      for (int i = 0; i < t; ++i) s -= Asm[t][i] * Wsm[i][j];
      Wsm[t][j] = s;
    }
    for (int t = 0; t < 64; ++t)
      Wb[pw0 + (size_t)t * 64 + j] = f2bf(Wsm[t][j]);
  }
}

// ---------------------------------------------------------------------------
// Persistent-state MFMA chain (identical to round-9 except V/O are bf16).
// 256 wgs x 512 threads. wg owns S[c0:c0+16][:] fp32 master + bf16 shadow.
// ---------------------------------------------------------------------------
__global__ __launch_bounds__(512) void chain_kernel(
    const u16* __restrict__ Qbf, const u16* __restrict__ Kbf,
    const u16* __restrict__ KT, const u16* __restrict__ Vbf,
    u16* __restrict__ Obf, const u16* __restrict__ Wb, const u16* __restrict__ Pb,
    float* __restrict__ Sglob, int lsh, int cpg, int g, int ngrp)
{
  const int wg = blockIdx.x;
  const int b = wg >> 6;
  const int sl = wg & 63;
  const int c0 = sl * 16;
  const int tgs = 1 << lsh;
  const int tid = threadIdx.x;
  const int lane = tid & 63;
  const int wave = tid >> 6;
  const int quad = lane >> 4, l16 = lane & 15;

  __shared__ float Ssl[16][1028];
  __shared__ u16 Sb[16][1040];
  __shared__ u16 rhsT[16][80];
  __shared__ u16 uT[16][80];

  if (g == 0) {
    for (int idx = tid; idx < 16 * 1024; idx += 512) {
      int r = idx >> 10, d = idx & 1023;
      Ssl[r][d] = 0.0f;
      Sb[r][d] = 0;
    }
  } else {
    for (int idx = tid; idx < 16 * 1024; idx += 512) {
      int r = idx >> 10, d = idx & 1023;
      float v = Sglob[((size_t)b * 1024 + c0 + r) * 1024 + d];
      Ssl[r][d] = v;
      Sb[r][d] = f2bf(v);
    }
  }
  __syncthreads();

  const bool isK = (wave < 4);
  const int mt = isK ? wave : (wave - 4);
  const int m0 = mt * 16;

  for (int cc = 0; cc < cpg; ++cc) {
    const int base = b * tgs + cc * CH;
    const size_t pw0 = ((size_t)(cc * B_ + b) * CH) * 64;

    floatx4 accS = {};
    {
      const u16* arow = (isK ? Kbf : Qbf) + (size_t)(base + m0 + l16) * 1024;
#pragma unroll 8
      for (int kk = 0; kk < 32; ++kk) {
        short8 a = *reinterpret_cast<const short8*>(&arow[kk * 32 + quad * 8]);
        short8 bs = *reinterpret_cast<const short8*>(&Sb[l16][kk * 32 + quad * 8]);
        accS = __builtin_amdgcn_mfma_f32_16x16x32_bf16(a, bs, accS, 0, 0, 0);
      }
    }

    if (isK) {
#pragma unroll
      for (int reg = 0; reg < 4; ++reg) {
        int t = m0 + quad * 4 + reg;
        float v = bf2f(Vbf[(size_t)(base + t) * 1024 + c0 + l16]);
        rhsT[l16][t] = f2bf(v - accS[reg]);
      }
    }
    __syncthreads();

    if (isK) {
      floatx4 uacc = {};
      const u16* wrow = &Wb[pw0 + (size_t)(m0 + l16) * 64];
#pragma unroll
      for (int kk = 0; kk < 2; ++kk) {
        short8 a = *reinterpret_cast<const short8*>(&wrow[kk * 32 + quad * 8]);
        short8 br = *reinterpret_cast<const short8*>(&rhsT[l16][kk * 32 + quad * 8]);
        uacc = __builtin_amdgcn_mfma_f32_16x16x32_bf16(a, br, uacc, 0, 0, 0);
      }
#pragma unroll
      for (int reg = 0; reg < 4; ++reg)
        uT[l16][m0 + quad * 4 + reg] = f2bf(uacc[reg]);
    }
    __syncthreads();

    if (!isK) {
      floatx4 oacc = accS;
      const u16* prow = &Pb[pw0 + (size_t)(m0 + l16) * 64];
#pragma unroll
      for (int kk = 0; kk < 2; ++kk) {
        short8 a = *reinterpret_cast<const short8*>(&prow[kk * 32 + quad * 8]);
        short8 bu = *reinterpret_cast<const short8*>(&uT[l16][kk * 32 + quad * 8]);
        oacc = __builtin_amdgcn_mfma_f32_16x16x32_bf16(a, bu, oacc, 0, 0, 0);
      }
#pragma unroll
      for (int reg = 0; reg < 4; ++reg) {
        int t = m0 + quad * 4 + reg;
        Obf[(size_t)(base + t) * 1024 + c0 + l16] = f2bf(oacc[reg]);
      }
    }

    {
      short8 ua0 = *reinterpret_cast<const short8*>(&uT[l16][quad * 8]);
      short8 ua1 = *reinterpret_cast<const short8*>(&uT[l16][32 + quad * 8]);
      const int d0w = wave * 128;
#pragma unroll
      for (int nt = 0; nt < 8; ++nt) {
        const int dn = d0w + nt * 16;
        const u16* ktrow = &KT[((size_t)b * 1024 + dn + l16) * tgs + cc * CH];
        short8 b0 = *reinterpret_cast<const short8*>(&ktrow[quad * 8]);
        short8 b1 = *reinterpret_cast<const short8*>(&ktrow[32 + quad * 8]);
        floatx4 cf;
        cf[0] = Ssl[quad * 4 + 0][dn + l16];
        cf[1] = Ssl[quad * 4 + 1][dn + l16];
        cf[2] = Ssl[quad * 4 + 2][dn + l16];
        cf[3] = Ssl[quad * 4 + 3][dn + l16];
        cf = __builtin_amdgcn_mfma_f32_16x16x32_bf16(ua0, b0, cf, 0, 0, 0);
        cf = __builtin_amdgcn_mfma_f32_16x16x32_bf16(ua1, b1, cf, 0, 0, 0);
#pragma unroll
        for (int reg = 0; reg < 4; ++reg) {
          Ssl[quad * 4 + reg][dn + l16] = cf[reg];
          Sb[quad * 4 + reg][dn + l16] = f2bf(cf[reg]);
        }
      }
    }
    __syncthreads();
  }

  if (g < ngrp - 1) {
    for (int idx = tid; idx < 16 * 1024; idx += 512) {
      int r = idx >> 10, d = idx & 1023;
      Sglob[((size_t)b * 1024 + c0 + r) * 1024 + d] = Ssl[r][d];
    }
  }
}

// ---------------------------------------------------------------------------
extern "C" void kernel_launch(void* const* d_in, const int* in_sizes, int n_in,
                              void* d_out, int out_size, void* d_ws, size_t ws_size,
                              hipStream_t stream) {
  const float* x  = (const float*)d_in[0];
  const float* Wq = (const float*)d_in[1];
  const float* Wk = (const float*)d_in[2];
  const float* Wv = (const float*)d_in[3];
  const float* Wo = (const float*)d_in[4];
  float* out = (float*)d_out;

  // tier: largest time-group that fits ws
  int lsh = 8;
  {
    const int cand[4] = {11, 10, 9, 8};
    for (int i = 0; i < 4; ++i) {
      size_t tgs = (size_t)1 << cand[i];
      size_t C = (size_t)B_ * tgs * 1024;
      size_t cpg = tgs / CH;
      size_t need = (size_t)B_ * T_ * 1024 * 2              // Xbf
                  + 4 * ((size_t)1024 * 1024 * 2)           // WT x4
                  + 5 * (C * 2)                             // Qbf,Kbf,Vbf,KT,Obf
                  + 2 * (cpg * B_ * CH * 64 * 2)            // Pb,Wb
                  + (size_t)B_ * 1024 * 1024 * 4            // Sglob
                  + 32768;
      if (need <= ws_size) { lsh = cand[i]; break; }
    }
  }
  const int tgs = 1 << lsh;
  const int cpg = tgs / CH;
  const int ngrp = T_ / tgs;
  const int rows = B_ * tgs;

  char* ws = (char*)d_ws;
  size_t off = 0;
  auto alloc = [&](size_t bytes) -> void* {
    void* p = ws + off;
    off += (bytes + 255) & ~(size_t)255;
    return p;
  };
  u16* Xbf = (u16*)alloc((size_t)B_ * T_ * 1024 * 2);
  u16* WqT = (u16*)alloc((size_t)1024 * 1024 * 2);
  u16* WkT = (u16*)alloc((size_t)1024 * 1024 * 2);
  u16* WvT = (u16*)alloc((size_t)1024 * 1024 * 2);
  u16* WoT = (u16*)alloc((size_t)1024 * 1024 * 2);
  u16* Qbf = (u16*)alloc((size_t)rows * 1024 * 2);
  u16* Kbf = (u16*)alloc((size_t)rows * 1024 * 2);
  u16* Vbf = (u16*)alloc((size_t)rows * 1024 * 2);
  u16* KT  = (u16*)alloc((size_t)rows * 1024 * 2);
  u16* Obf = (u16*)alloc((size_t)rows * 1024 * 2);
  u16* Pb  = (u16*)alloc((size_t)cpg * B_ * CH * 64 * 2);
  u16* Wb  = (u16*)alloc((size_t)cpg * B_ * CH * 64 * 2);
  float* Sglob = (float*)alloc((size_t)B_ * 1024 * 1024 * 4);

  xconv_kernel<<<B_ * T_, 256, 0, stream>>>(x, Xbf);
  wtrans_kernel<<<dim3(16, 16, 4), 256, 0, stream>>>(Wq, Wk, Wv, Wo, WqT, WkT, WvT, WoT);

  for (int g = 0; g < ngrp; ++g) {
    int tg = g * tgs;
    mgemm_qkv<<<dim3(rows / 128, 8, 3), 256, 0, stream>>>(Xbf, WqT, WkT, WvT,
                                                          Qbf, Kbf, Vbf, tg, lsh);
    knorm_kernel<<<rows, 256, 0, stream>>>(Kbf);
    ktrans_kernel<<<dim3(tgs / 64, 16, B_), 256, 0, stream>>>(Kbf, KT, tgs);
    attn_winv_kernel<<<dim3(cpg, B_), 256, 0, stream>>>(Qbf, Kbf, Pb, Wb, tgs);
    chain_kernel<<<256, 512, 0, stream>>>(Qbf, Kbf, KT, Vbf, Obf, Wb, Pb, Sglob,
                                          lsh, cpg, g, ngrp);
    mgemm_out<<<dim3(rows / 128, 8), 256, 0, stream>>>(Obf, WoT, out, tg, lsh);
  }
}

// Round 11
// 636.916 us; speedup vs baseline: 10.1551x; 1.0167x over previous
//
#include <hip/hip_runtime.h>

typedef unsigned short u16;
typedef __attribute__((ext_vector_type(8))) short short8;     // 8 bf16 (4 VGPRs)
typedef __attribute__((ext_vector_type(4))) float floatx4;    // 4 fp32 acc

#define B_ 4
#define T_ 2048
#define CH 64

__device__ __forceinline__ u16 f2bf(float f) {
  unsigned int x = __float_as_uint(f);
  return (u16)((x + 0x7FFFu + ((x >> 16) & 1u)) >> 16);
}
__device__ __forceinline__ float bf2f(u16 u) {
  union { unsigned int i; float f; } v; v.i = ((unsigned int)u) << 16; return v.f;
}

// ---------------------------------------------------------------------------
// x fp32 -> bf16 (full tensor). grid (B_*T_), 256 thr x 4 elems.
// ---------------------------------------------------------------------------
__global__ __launch_bounds__(256) void xconv_kernel(const float* __restrict__ x,
                                                    u16* __restrict__ Xbf) {
  size_t idx = ((size_t)blockIdx.x * 256 + threadIdx.x) * 4;
  float4 v = *reinterpret_cast<const float4*>(&x[idx]);
  ushort4 o;
  o.x = f2bf(v.x); o.y = f2bf(v.y); o.z = f2bf(v.z); o.w = f2bf(v.w);
  *reinterpret_cast<ushort4*>(&Xbf[idx]) = o;
}

// ---------------------------------------------------------------------------
// Weight transpose+convert: T[n][k] = bf16(W[k][n]). grid (16,16,4).
// ---------------------------------------------------------------------------
__global__ __launch_bounds__(256) void wtrans_kernel(
    const float* __restrict__ W0, const float* __restrict__ W1,
    const float* __restrict__ W2, const float* __restrict__ W3,
    u16* __restrict__ T0, u16* __restrict__ T1,
    u16* __restrict__ T2, u16* __restrict__ T3)
{
  const int z = blockIdx.z;
  const float* W = (z == 0) ? W0 : (z == 1) ? W1 : (z == 2) ? W2 : W3;
  u16* T = (z == 0) ? T0 : (z == 1) ? T1 : (z == 2) ? T2 : T3;
  const int k0 = blockIdx.x * 64, n0 = blockIdx.y * 64;
  const int tid = threadIdx.x;
  __shared__ float Tile[64][65];
#pragma unroll
  for (int i = 0; i < 4; ++i) {
    int lin = tid + i * 256;
    int r = lin >> 4, c4 = (lin & 15) * 4;
    *reinterpret_cast<float4*>(&Tile[r][c4]) =
        *reinterpret_cast<const float4*>(&W[(size_t)(k0 + r) * 1024 + n0 + c4]);
  }
  __syncthreads();
#pragma unroll
  for (int i = 0; i < 4; ++i) {
    int lin = tid + i * 256;
    int r = lin >> 4, c4 = (lin & 15) * 4;   // r: n-within, c4: k-within
    ushort4 o;
    o.x = f2bf(Tile[c4 + 0][r]); o.y = f2bf(Tile[c4 + 1][r]);
    o.z = f2bf(Tile[c4 + 2][r]); o.w = f2bf(Tile[c4 + 3][r]);
    *reinterpret_cast<ushort4*>(&T[(size_t)(n0 + r) * 1024 + k0 + c4]) = o;
  }
}

// ---------------------------------------------------------------------------
// MFMA GEMM for QKV. 128x128 tile, 4 waves (2x2), 4x4 of 16x16x32, BK=32.
// grid (rows/128, 8, 3).
// ---------------------------------------------------------------------------
__global__ __launch_bounds__(256) void mgemm_qkv(
    const u16* __restrict__ Xbf,
    const u16* __restrict__ WqT, const u16* __restrict__ WkT, const u16* __restrict__ WvT,
    u16* __restrict__ Qbf, u16* __restrict__ Kbf, u16* __restrict__ Vbf,
    int tg, int lsh)
{
  const int z = blockIdx.z;
  const u16* BT = (z == 0) ? WqT : ((z == 1) ? WkT : WvT);
  u16* O = (z == 0) ? Qbf : ((z == 1) ? Kbf : Vbf);
  const float scale = (z == 0) ? 0.03125f : 1.0f;
  const int r0 = blockIdx.x * 128, c0 = blockIdx.y * 128;
  const int tid = threadIdx.x;
  const int lane = tid & 63, wave = tid >> 6;
  const int quad = lane >> 4, l16 = lane & 15;
  const int wr = (wave >> 1) * 64, wc = (wave & 1) * 64;

  __shared__ u16 As[128][40];
  __shared__ u16 Bs[128][40];

  const int ar = tid >> 1, ac = (tid & 1) * 16;
  const int lr = r0 + ar;
  const int agrow = ((lr >> lsh) << 11) + tg + (lr & ((1 << lsh) - 1));
  const u16* aptr = &Xbf[(size_t)agrow * 1024 + ac];
  const u16* bptr = &BT[(size_t)(c0 + ar) * 1024 + ac];

  floatx4 acc[4][4] = {};
  for (int k0 = 0; k0 < 1024; k0 += 32) {
    float4 av0 = *reinterpret_cast<const float4*>(aptr + k0);
    float4 av1 = *reinterpret_cast<const float4*>(aptr + k0 + 8);
    float4 bv0 = *reinterpret_cast<const float4*>(bptr + k0);
    float4 bv1 = *reinterpret_cast<const float4*>(bptr + k0 + 8);
    __syncthreads();
    *reinterpret_cast<float4*>(&As[ar][ac]) = av0;
    *reinterpret_cast<float4*>(&As[ar][ac + 8]) = av1;
    *reinterpret_cast<float4*>(&Bs[ar][ac]) = bv0;
    *reinterpret_cast<float4*>(&Bs[ar][ac + 8]) = bv1;
    __syncthreads();
    short8 afr[4], bfr[4];
#pragma unroll
    for (int i = 0; i < 4; ++i) {
      afr[i] = *reinterpret_cast<const short8*>(&As[wr + i * 16 + l16][quad * 8]);
      bfr[i] = *reinterpret_cast<const short8*>(&Bs[wc + i * 16 + l16][quad * 8]);
    }
#pragma unroll
    for (int mi = 0; mi < 4; ++mi)
#pragma unroll
      for (int ni = 0; ni < 4; ++ni)
        acc[mi][ni] = __builtin_amdgcn_mfma_f32_16x16x32_bf16(afr[mi], bfr[ni], acc[mi][ni], 0, 0, 0);
  }
#pragma unroll
  for (int mi = 0; mi < 4; ++mi)
#pragma unroll
    for (int reg = 0; reg < 4; ++reg) {
      int row = r0 + wr + mi * 16 + quad * 4 + reg;
#pragma unroll
      for (int ni = 0; ni < 4; ++ni) {
        int col = c0 + wc + ni * 16 + l16;
        O[(size_t)row * 1024 + col] = f2bf(acc[mi][ni][reg] * scale);
      }
    }
}

// ---------------------------------------------------------------------------
// MFMA GEMM out-proj: fp32 out. grid (rows/128, 8)
// ---------------------------------------------------------------------------
__global__ __launch_bounds__(256) void mgemm_out(
    const u16* __restrict__ Obf, const u16* __restrict__ WoT,
    float* __restrict__ out, int tg, int lsh)
{
  const int r0 = blockIdx.x * 128, c0 = blockIdx.y * 128;
  const int tid = threadIdx.x;
  const int lane = tid & 63, wave = tid >> 6;
  const int quad = lane >> 4, l16 = lane & 15;
  const int wr = (wave >> 1) * 64, wc = (wave & 1) * 64;

  __shared__ u16 As[128][40];
  __shared__ u16 Bs[128][40];

  const int ar = tid >> 1, ac = (tid & 1) * 16;
  const u16* aptr = &Obf[(size_t)(r0 + ar) * 1024 + ac];
  const u16* bptr = &WoT[(size_t)(c0 + ar) * 1024 + ac];

  floatx4 acc[4][4] = {};
  for (int k0 = 0; k0 < 1024; k0 += 32) {
    float4 av0 = *reinterpret_cast<const float4*>(aptr + k0);
    float4 av1 = *reinterpret_cast<const float4*>(aptr + k0 + 8);
    float4 bv0 = *reinterpret_cast<const float4*>(bptr + k0);
    float4 bv1 = *reinterpret_cast<const float4*>(bptr + k0 + 8);
    __syncthreads();
    *reinterpret_cast<float4*>(&As[ar][ac]) = av0;
    *reinterpret_cast<float4*>(&As[ar][ac + 8]) = av1;
    *reinterpret_cast<float4*>(&Bs[ar][ac]) = bv0;
    *reinterpret_cast<float4*>(&Bs[ar][ac + 8]) = bv1;
    __syncthreads();
    short8 afr[4], bfr[4];
#pragma unroll
    for (int i = 0; i < 4; ++i) {
      afr[i] = *reinterpret_cast<const short8*>(&As[wr + i * 16 + l16][quad * 8]);
      bfr[i] = *reinterpret_cast<const short8*>(&Bs[wc + i * 16 + l16][quad * 8]);
    }
#pragma unroll
    for (int mi = 0; mi < 4; ++mi)
#pragma unroll
      for (int ni = 0; ni < 4; ++ni)
        acc[mi][ni] = __builtin_amdgcn_mfma_f32_16x16x32_bf16(afr[mi], bfr[ni], acc[mi][ni], 0, 0, 0);
  }
#pragma unroll
  for (int mi = 0; mi < 4; ++mi)
#pragma unroll
    for (int reg = 0; reg < 4; ++reg) {
      int lr = r0 + wr + mi * 16 + quad * 4 + reg;
      int grow = ((lr >> lsh) << 11) + tg + (lr & ((1 << lsh) - 1));
#pragma unroll
      for (int ni = 0; ni < 4; ++ni) {
        int col = c0 + wc + ni * 16 + l16;
        out[(size_t)grow * 1024 + col] = acc[mi][ni][reg];
      }
    }
}

// ---------------------------------------------------------------------------
// Row-normalize Kbf in place (bf16, fp32 math). grid (rows).
// ---------------------------------------------------------------------------
__global__ __launch_bounds__(256) void knorm_kernel(u16* __restrict__ Kbf) {
  const int row = blockIdx.x;
  const int tid = threadIdx.x;
  ushort4 v4 = *reinterpret_cast<const ushort4*>(&Kbf[(size_t)row * 1024 + tid * 4]);
  float a = bf2f(v4.x), b = bf2f(v4.y), c = bf2f(v4.z), d = bf2f(v4.w);
  float ss = a * a + b * b + c * c + d * d;
#pragma unroll
  for (int off = 32; off > 0; off >>= 1) ss += __shfl_down(ss, off);
  __shared__ float wsum[4];
  if ((tid & 63) == 0) wsum[tid >> 6] = ss;
  __syncthreads();
  float tot = wsum[0] + wsum[1] + wsum[2] + wsum[3];
  float inv = 1.0f / fmaxf(sqrtf(tot), 1e-12f);
  ushort4 o;
  o.x = f2bf(a * inv); o.y = f2bf(b * inv); o.z = f2bf(c * inv); o.w = f2bf(d * inv);
  *reinterpret_cast<ushort4*>(&Kbf[(size_t)row * 1024 + tid * 4]) = o;
}

// ---------------------------------------------------------------------------
// Transpose Kbf -> KT[b][d][t_local] (bf16). grid (tgs/64, 16, B_), 256 thr.
// ---------------------------------------------------------------------------
__global__ __launch_bounds__(256) void ktrans_kernel(const u16* __restrict__ Kbf,
                                                     u16* __restrict__ KT,
                                                     int tgs) {
  const int t0 = blockIdx.x * 64;
  const int d0 = blockIdx.y * 64;
  const int b = blockIdx.z;
  const int tid = threadIdx.x;
  __shared__ u16 Tile[64][68];
#pragma unroll
  for (int i = 0; i < 4; ++i) {
    int lin = tid + i * 256;
    int r = lin >> 4, c4 = (lin & 15) * 4;
    *reinterpret_cast<ushort4*>(&Tile[r][c4]) =
        *reinterpret_cast<const ushort4*>(&Kbf[(size_t)(b * tgs + t0 + r) * 1024 + d0 + c4]);
  }
  __syncthreads();
#pragma unroll
  for (int i = 0; i < 4; ++i) {
    int lin = tid + i * 256;
    int r = lin >> 4, c4 = (lin & 15) * 4;
    ushort4 o;
    o.x = Tile[c4 + 0][r]; o.y = Tile[c4 + 1][r];
    o.z = Tile[c4 + 2][r]; o.w = Tile[c4 + 3][r];
    *reinterpret_cast<ushort4*>(&KT[((size_t)b * 1024 + d0 + r) * tgs + t0 + c4]) = o;
  }
}

// ---------------------------------------------------------------------------
// Per (chunk, batch): MFMA QK^T/KK^T -> P and A -> W=(I+A)^{-1} -> bf16.
// grid (cpg, B_), 256 threads.
// ---------------------------------------------------------------------------
__global__ __launch_bounds__(256) void attn_winv_kernel(
    const u16* __restrict__ Qbf, const u16* __restrict__ Kbf,
    u16* __restrict__ Pb, u16* __restrict__ Wb, int tgs)
{
  const int cc = blockIdx.x;
  const int b = blockIdx.y;
  const int base = b * tgs + cc * CH;
  const int tid = threadIdx.x;
  const int lane = tid & 63;
  const int wave = tid >> 6;
  const int quad = lane >> 4, l16 = lane & 15;
  const int m0 = wave * 16;

  __shared__ float Asm[64][64];
  __shared__ float Wsm[64][65];

  floatx4 accA[4] = {};
  floatx4 accP[4] = {};
  const u16* arowK = &Kbf[(size_t)(base + m0 + l16) * 1024];
  const u16* arowQ = &Qbf[(size_t)(base + m0 + l16) * 1024];
#pragma unroll 4
  for (int kk = 0; kk < 32; ++kk) {
    short8 aK = *reinterpret_cast<const short8*>(&arowK[kk * 32 + quad * 8]);
    short8 aQ = *reinterpret_cast<const short8*>(&arowQ[kk * 32 + quad * 8]);
#pragma unroll
    for (int nt = 0; nt < 4; ++nt) {
      short8 bK = *reinterpret_cast<const short8*>(
          &Kbf[(size_t)(base + nt * 16 + l16) * 1024 + kk * 32 + quad * 8]);
      accA[nt] = __builtin_amdgcn_mfma_f32_16x16x32_bf16(aK, bK, accA[nt], 0, 0, 0);
      accP[nt] = __builtin_amdgcn_mfma_f32_16x16x32_bf16(aQ, bK, accP[nt], 0, 0, 0);
    }
  }
  const size_t pw0 = ((size_t)(cc * B_ + b) * CH) * 64;
#pragma unroll
  for (int nt = 0; nt < 4; ++nt) {
#pragma unroll
    for (int reg = 0; reg < 4; ++reg) {
      int t = m0 + quad * 4 + reg;
      int i = nt * 16 + l16;
      Asm[t][i] = (i < t) ? accA[nt][reg] : 0.0f;
      Pb[pw0 + (size_t)t * 64 + i] = f2bf((i <= t) ? accP[nt][reg] : 0.0f);
    }
  }
  __syncthreads();

  if (tid < 64) {
    const int j = tid;
    for (int t = 0; t < 64; ++t) {
      float s = (t == j) ? 1.0f : 0.0f;
      for (int i = 0; i < t; ++i) s -= Asm[t][i] * Wsm[i][j];
      Wsm[t][j] = s;
    }
    for (int t = 0; t < 64; ++t)
      Wb[pw0 + (size_t)t * 64 + j] = f2bf(Wsm[t][j]);
  }
}

// ---------------------------------------------------------------------------
// Persistent-state MFMA chain, register-resident fp32 S.
// 256 wgs x 512 threads. wg owns S[c0:c0+16][0:1024]:
//   fp32 master in VGPRs (Sreg[8] per lane; fixed (wave,nt,reg,lane)->(c,d)
//   map from the MFMA C/D layout), bf16 shadow Sb in LDS for phase-A B-frags.
// Phase A: 4 independent accumulator chains (ILP). KT/W/P/V prefetched at
// chunk top. LDS ~39 KB.
// ---------------------------------------------------------------------------
__global__ __launch_bounds__(512, 2) void chain_kernel(
    const u16* __restrict__ Qbf, const u16* __restrict__ Kbf,
    const u16* __restrict__ KT, const u16* __restrict__ Vbf,
    u16* __restrict__ Obf, const u16* __restrict__ Wb, const u16* __restrict__ Pb,
    float* __restrict__ Sglob, int lsh, int cpg, int g, int ngrp)
{
  const int wg = blockIdx.x;
  const int b = wg >> 6;
  const int sl = wg & 63;
  const int c0 = sl * 16;
  const int tgs = 1 << lsh;
  const int tid = threadIdx.x;
  const int lane = tid & 63;
  const int wave = tid >> 6;
  const int quad = lane >> 4, l16 = lane & 15;
  const int d0w = wave * 128;
  const bool isK = (wave < 4);
  const int m0 = (isK ? wave : (wave - 4)) * 16;

  __shared__ u16 Sb[16][1048];   // bf16 shadow (524 words/row = 12 mod 32)
  __shared__ u16 rhsT[16][88];   // (V - KS)^T bf16 (44 words = 12 mod 32)
  __shared__ u16 uT[16][88];     // u^T bf16

  // fp32 master S in registers: Sreg[nt][reg] <-> S[c=quad*4+reg][d=d0w+nt*16+l16]
  floatx4 Sreg[8];
  if (g == 0) {
#pragma unroll
    for (int nt = 0; nt < 8; ++nt) Sreg[nt] = (floatx4){0.f, 0.f, 0.f, 0.f};
    for (int idx = tid; idx < 16 * 256; idx += 512) {
      int r = idx >> 8, d4 = (idx & 255) * 4;
      ushort4 z4 = {0, 0, 0, 0};
      *reinterpret_cast<ushort4*>(&Sb[r][d4]) = z4;
    }
  } else {
#pragma unroll
    for (int nt = 0; nt < 8; ++nt)
#pragma unroll
      for (int reg = 0; reg < 4; ++reg)
        Sreg[nt][reg] = Sglob[((size_t)b * 1024 + c0 + quad * 4 + reg) * 1024 +
                              d0w + nt * 16 + l16];
    for (int idx = tid; idx < 16 * 1024; idx += 512) {
      int r = idx >> 10, d = idx & 1023;
      Sb[r][d] = f2bf(Sglob[((size_t)b * 1024 + c0 + r) * 1024 + d]);
    }
  }
  __syncthreads();

  for (int cc = 0; cc < cpg; ++cc) {
    const int base = b * tgs + cc * CH;
    const size_t pw0 = ((size_t)(cc * B_ + b) * CH) * 64;

    // ---- prefetches (independent of all in-chunk LDS state) ----
    float vv[4];
    if (isK) {
#pragma unroll
      for (int reg = 0; reg < 4; ++reg)
        vv[reg] = bf2f(Vbf[(size_t)(base + m0 + quad * 4 + reg) * 1024 + c0 + l16]);
    }
    short8 wpf0, wpf1;   // W row frags (K-waves) or P row frags (Q-waves)
    {
      const u16* row = (isK ? Wb : Pb) + pw0 + (size_t)(m0 + l16) * 64;
      wpf0 = *reinterpret_cast<const short8*>(row + quad * 8);
      wpf1 = *reinterpret_cast<const short8*>(row + 32 + quad * 8);
    }
    short8 ktf[8][2];    // KT B-frags for phase C
#pragma unroll
    for (int nt = 0; nt < 8; ++nt) {
      const u16* ktrow = &KT[((size_t)b * 1024 + d0w + nt * 16 + l16) * tgs + cc * CH];
      ktf[nt][0] = *reinterpret_cast<const short8*>(ktrow + quad * 8);
      ktf[nt][1] = *reinterpret_cast<const short8*>(ktrow + 32 + quad * 8);
    }

    // ---- phase A: KS (K-waves) / QS (Q-waves), 4 independent chains ----
    floatx4 ac0 = {}, ac1 = {}, ac2 = {}, ac3 = {};
    {
      const u16* arow = (isK ? Kbf : Qbf) + (size_t)(base + m0 + l16) * 1024;
#pragma unroll
      for (int kk8 = 0; kk8 < 8; ++kk8) {
        const int kb = kk8 * 4;
        short8 A0 = *reinterpret_cast<const short8*>(&arow[(kb + 0) * 32 + quad * 8]);
        short8 A1 = *reinterpret_cast<const short8*>(&arow[(kb + 1) * 32 + quad * 8]);
        short8 A2 = *reinterpret_cast<const short8*>(&arow[(kb + 2) * 32 + quad * 8]);
        short8 A3 = *reinterpret_cast<const short8*>(&arow[(kb + 3) * 32 + quad * 8]);
        short8 B0 = *reinterpret_cast<const short8*>(&Sb[l16][(kb + 0) * 32 + quad * 8]);
        short8 B1 = *reinterpret_cast<const short8*>(&Sb[l16][(kb + 1) * 32 + quad * 8]);
        short8 B2 = *reinterpret_cast<const short8*>(&Sb[l16][(kb + 2) * 32 + quad * 8]);
        short8 B3 = *reinterpret_cast<const short8*>(&Sb[l16][(kb + 3) * 32 + quad * 8]);
        ac0 = __builtin_amdgcn_mfma_f32_16x16x32_bf16(A0, B0, ac0, 0, 0, 0);
        ac1 = __builtin_amdgcn_mfma_f32_16x16x32_bf16(A1, B1, ac1, 0, 0, 0);
        ac2 = __builtin_amdgcn_mfma_f32_16x16x32_bf16(A2, B2, ac2, 0, 0, 0);
        ac3 = __builtin_amdgcn_mfma_f32_16x16x32_bf16(A3, B3, ac3, 0, 0, 0);
      }
    }
    floatx4 accS = (ac0 + ac1) + (ac2 + ac3);

    // ---- rhs = V - KS (K-waves) ----
    if (isK) {
#pragma unroll
      for (int reg = 0; reg < 4; ++reg)
        rhsT[l16][m0 + quad * 4 + reg] = f2bf(vv[reg] - accS[reg]);
    }
    __syncthreads();

    // ---- u = W * rhs (K-waves) ----
    if (isK) {
      floatx4 uacc = {};
      short8 br0 = *reinterpret_cast<const short8*>(&rhsT[l16][quad * 8]);
      short8 br1 = *reinterpret_cast<const short8*>(&rhsT[l16][32 + quad * 8]);
      uacc = __builtin_amdgcn_mfma_f32_16x16x32_bf16(wpf0, br0, uacc, 0, 0, 0);
      uacc = __builtin_amdgcn_mfma_f32_16x16x32_bf16(wpf1, br1, uacc, 0, 0, 0);
#pragma unroll
      for (int reg = 0; reg < 4; ++reg)
        uT[l16][m0 + quad * 4 + reg] = f2bf(uacc[reg]);
    }
    __syncthreads();

    // ---- o = QS + P*u (Q-waves) ----
    if (!isK) {
      floatx4 oacc = accS;
      short8 bu0 = *reinterpret_cast<const short8*>(&uT[l16][quad * 8]);
      short8 bu1 = *reinterpret_cast<const short8*>(&uT[l16][32 + quad * 8]);
      oacc = __builtin_amdgcn_mfma_f32_16x16x32_bf16(wpf0, bu0, oacc, 0, 0, 0);
      oacc = __builtin_amdgcn_mfma_f32_16x16x32_bf16(wpf1, bu1, oacc, 0, 0, 0);
#pragma unroll
      for (int reg = 0; reg < 4; ++reg) {
        int t = m0 + quad * 4 + reg;
        Obf[(size_t)(base + t) * 1024 + c0 + l16] = f2bf(oacc[reg]);
      }
    }

    // ---- phase C: Sreg += u^T K (wave covers d0w..d0w+127) ----
    {
      short8 ua0 = *reinterpret_cast<const short8*>(&uT[l16][quad * 8]);
      short8 ua1 = *reinterpret_cast<const short8*>(&uT[l16][32 + quad * 8]);
#pragma unroll
      for (int nt = 0; nt < 8; ++nt) {
        floatx4 cf = Sreg[nt];
        cf = __builtin_amdgcn_mfma_f32_16x16x32_bf16(ua0, ktf[nt][0], cf, 0, 0, 0);
        cf = __builtin_amdgcn_mfma_f32_16x16x32_bf16(ua1, ktf[nt][1], cf, 0, 0, 0);
        Sreg[nt] = cf;
        const int dn = d0w + nt * 16;
#pragma unroll
        for (int reg = 0; reg < 4; ++reg)
          Sb[quad * 4 + reg][dn + l16] = f2bf(cf[reg]);
      }
    }
    __syncthreads();
  }

  // spill S for next group (only for small-ws tiers; full tier has ngrp==1)
  if (g < ngrp - 1) {
#pragma unroll
    for (int nt = 0; nt < 8; ++nt)
#pragma unroll
      for (int reg = 0; reg < 4; ++reg)
        Sglob[((size_t)b * 1024 + c0 + quad * 4 + reg) * 1024 + d0w + nt * 16 + l16] =
            Sreg[nt][reg];
  }
}

// ---------------------------------------------------------------------------
extern "C" void kernel_launch(void* const* d_in, const int* in_sizes, int n_in,
                              void* d_out, int out_size, void* d_ws, size_t ws_size,
                              hipStream_t stream) {
  const float* x  = (const float*)d_in[0];
  const float* Wq = (const float*)d_in[1];
  const float* Wk = (const float*)d_in[2];
  const float* Wv = (const float*)d_in[3];
  const float* Wo = (const float*)d_in[4];
  float* out = (float*)d_out;

  // tier: largest time-group that fits ws
  int lsh = 8;
  {
    const int cand[4] = {11, 10, 9, 8};
    for (int i = 0; i < 4; ++i) {
      size_t tgs = (size_t)1 << cand[i];
      size_t C = (size_t)B_ * tgs * 1024;
      size_t cpg = tgs / CH;
      size_t need = (size_t)B_ * T_ * 1024 * 2              // Xbf
                  + 4 * ((size_t)1024 * 1024 * 2)           // WT x4
                  + 5 * (C * 2)                             // Qbf,Kbf,Vbf,KT,Obf
                  + 2 * (cpg * B_ * CH * 64 * 2)            // Pb,Wb
                  + (size_t)B_ * 1024 * 1024 * 4            // Sglob
                  + 32768;
      if (need <= ws_size) { lsh = cand[i]; break; }
    }
  }
  const int tgs = 1 << lsh;
  const int cpg = tgs / CH;
  const int ngrp = T_ / tgs;
  const int rows = B_ * tgs;

  char* ws = (char*)d_ws;
  size_t off = 0;
  auto alloc = [&](size_t bytes) -> void* {
    void* p = ws + off;
    off += (bytes + 255) & ~(size_t)255;
    return p;
  };
  u16* Xbf = (u16*)alloc((size_t)B_ * T_ * 1024 * 2);
  u16* WqT = (u16*)alloc((size_t)1024 * 1024 * 2);
  u16* WkT = (u16*)alloc((size_t)1024 * 1024 * 2);
  u16* WvT = (u16*)alloc((size_t)1024 * 1024 * 2);
  u16* WoT = (u16*)alloc((size_t)1024 * 1024 * 2);
  u16* Qbf = (u16*)alloc((size_t)rows * 1024 * 2);
  u16* Kbf = (u16*)alloc((size_t)rows * 1024 * 2);
  u16* Vbf = (u16*)alloc((size_t)rows * 1024 * 2);
  u16* KT  = (u16*)alloc((size_t)rows * 1024 * 2);
  u16* Obf = (u16*)alloc((size_t)rows * 1024 * 2);
  u16* Pb  = (u16*)alloc((size_t)cpg * B_ * CH * 64 * 2);
  u16* Wb  = (u16*)alloc((size_t)cpg * B_ * CH * 64 * 2);
  float* Sglob = (float*)alloc((size_t)B_ * 1024 * 1024 * 4);

  xconv_kernel<<<B_ * T_, 256, 0, stream>>>(x, Xbf);
  wtrans_kernel<<<dim3(16, 16, 4), 256, 0, stream>>>(Wq, Wk, Wv, Wo, WqT, WkT, WvT, WoT);

  for (int g = 0; g < ngrp; ++g) {
    int tg = g * tgs;
    mgemm_qkv<<<dim3(rows / 128, 8, 3), 256, 0, stream>>>(Xbf, WqT, WkT, WvT,
                                                          Qbf, Kbf, Vbf, tg, lsh);
    knorm_kernel<<<rows, 256, 0, stream>>>(Kbf);
    ktrans_kernel<<<dim3(tgs / 64, 16, B_), 256, 0, stream>>>(Kbf, KT, tgs);
    attn_winv_kernel<<<dim3(cpg, B_), 256, 0, stream>>>(Qbf, Kbf, Pb, Wb, tgs);
    chain_kernel<<<256, 512, 0, stream>>>(Qbf, Kbf, KT, Vbf, Obf, Wb, Pb, Sglob,
                                          lsh, cpg, g, ngrp);
    mgemm_out<<<dim3(rows / 128, 8), 256, 0, stream>>>(Obf, WoT, out, tg, lsh);
  }
}